// Round 8
// baseline (2177.772 us; speedup 1.0000x reference)
//
#include <hip/hip_runtime.h>
#include <hip/hip_bf16.h>
#include <cstdint>

using bf16 = __hip_bfloat16;

static constexpr int B = 2;
static constexpr int N = 2048;
static constexpr int KNN = 32;
static constexpr int FD = 480;
static constexpr float EPS = 1e-5f;
static constexpr float SLOPE = 0.2f;

// ---------------- workspace layout (floats), all compile-time ----------------
static constexpr size_t N_XF = (size_t)B * N * 3;
static constexpr size_t N_FEATS = (size_t)B * N * FD;
static constexpr size_t N_DIST = (size_t)B * N * N;
static constexpr size_t N_IDX = (size_t)B * N * KNN;
static constexpr size_t O_XF = 0;
static constexpr size_t O_FEATS = O_XF + N_XF;
static constexpr size_t O_DIST = O_FEATS + N_FEATS;
static constexpr size_t O_IDX = O_DIST + N_DIST;
static constexpr size_t O_WT0 = O_IDX + N_IDX;
static constexpr size_t O_WT1 = O_WT0 + 192;
static constexpr size_t O_WT2 = O_WT1 + 4096;
static constexpr size_t O_WT3 = O_WT2 + 16384;
static constexpr size_t O_WHT = O_WT3 + 65536;
static constexpr size_t O_F1W = O_WHT + 61440;
static constexpr size_t O_F1B = O_F1W + 16384;
static constexpr size_t O_F2W = O_F1B + 128;
static constexpr size_t O_F2B = O_F2W + 16384;
static constexpr size_t O_FLAG = O_F2B + 128;
static constexpr size_t O_CS0 = O_FLAG + 16;   // zero region starts here
static constexpr size_t O_CS1 = O_CS0 + 128;
static constexpr size_t O_CS2 = O_CS1 + 256;
static constexpr size_t O_CS3 = O_CS2 + 512;
static constexpr size_t O_FSUM = O_CS3 + 1024;
static constexpr size_t O_FSS = O_FSUM + 256;
static constexpr size_t O_FMAX = O_FSS + 256;
static constexpr size_t O_END = O_FMAX + 256;
static constexpr size_t N_ZERO = O_END - O_CS0;

__device__ __forceinline__ float lrelu(float x) { return x >= 0.f ? x : SLOPE * x; }

__device__ __forceinline__ float load_in(const void* p, int i, int isf32) {
  return isf32 ? ((const float*)p)[i] : __bfloat162float(((const bf16*)p)[i]);
}

// ---------------------------------------------------------------- prep (fused)
static constexpr int PREP_TOTAL =
    (int)(N_XF + 192 + 4096 + 16384 + 65536 + 61440 + 16384 + 128 + 16384 + 128 + N_ZERO);

__global__ __launch_bounds__(256) void prep_kernel(
    const void* __restrict__ x, const void* __restrict__ W0, const void* __restrict__ W1,
    const void* __restrict__ W2, const void* __restrict__ W3, const void* __restrict__ Wh,
    const void* __restrict__ fc1w, const void* __restrict__ fc1b,
    const void* __restrict__ fc2w, const void* __restrict__ fc2b, float* __restrict__ ws) {
  __shared__ float red[256];
  const unsigned short* xr = (const unsigned short*)x;
  float mx = 0.f;
  for (int i = threadIdx.x; i < B * N * 3; i += 256) {
    float v = __uint_as_float(((unsigned)xr[i]) << 16);
    v = fabsf(v);
    if (!(v < 1e30f)) v = 1e30f;  // NaN/inf -> huge
    mx = fmaxf(mx, v);
  }
  red[threadIdx.x] = mx;
  __syncthreads();
  for (int s = 128; s > 0; s >>= 1) {
    if (threadIdx.x < s) red[threadIdx.x] = fmaxf(red[threadIdx.x], red[threadIdx.x + s]);
    __syncthreads();
  }
  int isf = red[0] > 1e3f ? 1 : 0;
  if (blockIdx.x == 0 && threadIdx.x == 0) ((int*)(ws + O_FLAG))[0] = isf;

  int idx = blockIdx.x * 256 + threadIdx.x;
  if (idx < (int)N_XF) { ws[O_XF + idx] = load_in(x, idx, isf); return; }
  idx -= (int)N_XF;
  if (idx < 192) {
    int o = idx / 6, c = idx - o * 6;
    ws[O_WT0 + c * 32 + o] = load_in(W0, idx, isf);
    return;
  }
  idx -= 192;
  if (idx < 4096) {
    int o = idx >> 6, c = idx & 63;
    ws[O_WT1 + c * 64 + o] = load_in(W1, idx, isf);
    return;
  }
  idx -= 4096;
  if (idx < 16384) {
    int o = idx >> 7, c = idx & 127;
    ws[O_WT2 + c * 128 + o] = load_in(W2, idx, isf);
    return;
  }
  idx -= 16384;
  if (idx < 65536) {
    int o = idx >> 8, c = idx & 255;
    ws[O_WT3 + c * 256 + o] = load_in(W3, idx, isf);
    return;
  }
  idx -= 65536;
  if (idx < 61440) {
    int o = idx / 480, c = idx - o * 480;
    ws[O_WHT + c * 128 + o] = load_in(Wh, idx, isf);
    return;
  }
  idx -= 61440;
  if (idx < 16384) { ws[O_F1W + idx] = load_in(fc1w, idx, isf); return; }
  idx -= 16384;
  if (idx < 128) { ws[O_F1B + idx] = load_in(fc1b, idx, isf); return; }
  idx -= 128;
  if (idx < 16384) { ws[O_F2W + idx] = load_in(fc2w, idx, isf); return; }
  idx -= 16384;
  if (idx < 128) { ws[O_F2B + idx] = load_in(fc2b, idx, isf); return; }
  idx -= 128;
  if (idx < (int)N_ZERO) ws[O_CS0 + idx] = 0.f;
}

// ---------------------------------------------------------------- dist (sq fused)
template <int C>
__global__ __launch_bounds__(256) void dist_kernel(const float* __restrict__ h, int hstride,
                                                   float* __restrict__ dist) {
  constexpr int CW = 16;
  __shared__ float Ast[CW][132];
  __shared__ float Bst[CW][132];
  __shared__ float sqn[128], sqm[128];
  int b = blockIdx.z;
  int n0 = blockIdx.y * 128, m0 = blockIdx.x * 128;
  int tid = threadIdx.x;
  int tx = tid & 15, ty = tid >> 4;
  int rr = tid & 127;
  float dot[8][8] = {};
  float sqacc = 0.f;
  for (int cc = 0; cc < C; cc += CW) {
    for (int i = tid; i < 128 * CW; i += 256) {
      int c = i & 15, r = i >> 4;
      int gc = cc + c;
      float av = 0.f, bv = 0.f;
      if (gc < C) {
        av = h[(size_t)(b * N + n0 + r) * hstride + gc];
        bv = h[(size_t)(b * N + m0 + r) * hstride + gc];
      }
      Ast[c][r] = av;
      Bst[c][r] = bv;
    }
    __syncthreads();
    if (tid < 128) {
#pragma unroll
      for (int c = 0; c < CW; ++c) { float v = Ast[c][rr]; sqacc += v * v; }
    } else {
#pragma unroll
      for (int c = 0; c < CW; ++c) { float v = Bst[c][rr]; sqacc += v * v; }
    }
#pragma unroll
    for (int c = 0; c < CW; ++c) {
      float av[8], bv[8];
#pragma unroll
      for (int i = 0; i < 8; ++i) av[i] = Ast[c][ty * 8 + i];
#pragma unroll
      for (int j = 0; j < 8; ++j) bv[j] = Bst[c][tx * 8 + j];
#pragma unroll
      for (int i = 0; i < 8; ++i)
#pragma unroll
        for (int j = 0; j < 8; ++j) dot[i][j] += av[i] * bv[j];
    }
    __syncthreads();
  }
  if (tid < 128) sqn[rr] = sqacc; else sqm[rr] = sqacc;
  __syncthreads();
#pragma unroll
  for (int i = 0; i < 8; ++i) {
    int nn = n0 + ty * 8 + i;
    float sn = sqn[ty * 8 + i];
#pragma unroll
    for (int jq = 0; jq < 2; ++jq) {
      float4 w;
      w.x = sn + sqm[tx * 8 + jq * 4 + 0] - 2.f * dot[i][jq * 4 + 0];
      w.y = sn + sqm[tx * 8 + jq * 4 + 1] - 2.f * dot[i][jq * 4 + 1];
      w.z = sn + sqm[tx * 8 + jq * 4 + 2] - 2.f * dot[i][jq * 4 + 2];
      w.w = sn + sqm[tx * 8 + jq * 4 + 3] - 2.f * dot[i][jq * 4 + 3];
      *reinterpret_cast<float4*>(&dist[(size_t)(b * N + nn) * N + m0 + tx * 8 + jq * 4]) = w;
    }
  }
}

__device__ __forceinline__ unsigned long long wave_min_u64(unsigned long long v) {
#pragma unroll
  for (int m = 1; m < 64; m <<= 1) {
    unsigned lo = (unsigned)v;
    unsigned hi = (unsigned)(v >> 32);
    unsigned olo = (unsigned)__shfl_xor((int)lo, m, 64);
    unsigned ohi = (unsigned)__shfl_xor((int)hi, m, 64);
    unsigned long long ov = ((unsigned long long)ohi << 32) | olo;
    if (ov < v) v = ov;
  }
  return v;
}

__global__ __launch_bounds__(256) void select_kernel(const float* __restrict__ dist,
                                                     int* __restrict__ idxb) {
  int row = blockIdx.x * 4 + (threadIdx.x >> 6);  // b*N + n
  int lane = threadIdx.x & 63;
  const float* drow = dist + (size_t)row * N;
  unsigned long long key[32];
#pragma unroll
  for (int j = 0; j < 32; ++j) {
    int m = j * 64 + lane;
    unsigned u = __float_as_uint(drow[m]);
    u = (u & 0x80000000u) ? ~u : (u | 0x80000000u);
    key[j] = ((unsigned long long)u << 32) | (unsigned)m;
  }
  unsigned long long lmin = key[0];
#pragma unroll
  for (int j = 1; j < 32; ++j) lmin = key[j] < lmin ? key[j] : lmin;
  unsigned saved = 0;
  for (int it = 0; it <= KNN; ++it) {
    unsigned long long gmin = wave_min_u64(lmin);
    if (it > 0 && lane == it - 1) saved = (unsigned)(gmin & 0xFFFFFFFFull);
    if (lmin == gmin) {
#pragma unroll
      for (int j = 0; j < 32; ++j)
        if (key[j] == gmin) key[j] = ~0ull;
      lmin = key[0];
#pragma unroll
      for (int j = 1; j < 32; ++j) lmin = key[j] < lmin ? key[j] : lmin;
    }
  }
  if (lane < KNN) idxb[row * KNN + lane] = (int)saved;
}

// ---------------------------------------------------------------- edge conv, small (R4-proven)
template <int C, int O>
__global__ __launch_bounds__(256) void edge_small_kernel(const float* __restrict__ h, int hstride,
                                                         const int* __restrict__ idxb,
                                                         const float* __restrict__ Wt,
                                                         float* __restrict__ cstats,
                                                         float* __restrict__ featdst) {
  constexpr int KG = 256 / O;
  constexpr int KPG = KNN / KG;
  int bn = blockIdx.x;
  int b = bn >> 11;
  int tid = threadIdx.x;
  int o = tid % O;
  int kg = tid / O;

  __shared__ __align__(16) float nbr[KNN][C];
  __shared__ float cen[C];
  __shared__ int knn[KNN];
  __shared__ float red[3][KG][O];

  const float* hrow = h + (size_t)bn * hstride;
  if (tid < C) cen[tid] = hrow[tid];
  if (tid < KNN) knn[tid] = idxb[bn * KNN + tid];
  __syncthreads();
  for (int i = tid; i < KNN * C; i += 256) {
    int k = i / C, c = i - k * C;
    nbr[k][c] = h[(size_t)(b * N + knn[k]) * hstride + c];
  }
  __syncthreads();

  float ecen = 0.f;
  for (int c = 0; c < C; ++c)
    ecen += (Wt[(C + c) * O + o] - Wt[c * O + o]) * cen[c];

  float acc[KPG];
#pragma unroll
  for (int j = 0; j < KPG; ++j) acc[j] = ecen;

  for (int c = 0; c < C; ++c) {
    float w = Wt[c * O + o];
#pragma unroll
    for (int j = 0; j < KPG; ++j) acc[j] += w * nbr[kg * KPG + j][c];
  }

  float s = 0.f, ss = 0.f, mx = -3.4e38f;
#pragma unroll
  for (int j = 0; j < KPG; ++j) {
    float e = acc[j];
    s += e;
    ss += e * e;
    mx = fmaxf(mx, e);
  }

  red[0][kg][o] = s;
  red[1][kg][o] = ss;
  red[2][kg][o] = mx;
  __syncthreads();
  if (kg == 0) {
#pragma unroll
    for (int g = 1; g < KG; ++g) {
      s += red[0][g][o];
      ss += red[1][g][o];
      mx = fmaxf(mx, red[2][g][o]);
    }
    atomicAdd(&cstats[(b * O + o) * 2 + 0], s);
    atomicAdd(&cstats[(b * O + o) * 2 + 1], ss);
    featdst[(size_t)bn * FD + o] = mx;
  }
}

// ---------------------------------------------------------------- edge conv, tiled
// 8 outputs x KT k per thread. acc: 1-D constant-indexed only; nbr/weights via
// named float4 + .x/.y/.z/.w (R4-proven anti-spill idioms). Weights from
// global (L2 path, parallel to LDS pipe); nbr from LDS (broadcast layout).
template <int C, int O>
__global__ __launch_bounds__(256) void edge_tiled_kernel(const float* __restrict__ h, int hstride,
                                                         const int* __restrict__ idxb,
                                                         const float* __restrict__ Wt,  // [2C][O]
                                                         float* __restrict__ cstats,
                                                         float* __restrict__ featdst) {
  constexpr int OG = O / 8;     // o-groups per block
  constexpr int KG = 256 / OG;  // k-groups
  constexpr int KT = KNN / KG;  // k per thread (4 / 2 / 1)
  constexpr int CP = C + 4;
  int bn = blockIdx.x;
  int b = bn >> 11;
  int tid = threadIdx.x;
  int og = tid & (OG - 1);
  int kg = tid / OG;
  int o0 = og * 8;
  int kbase = kg * KT;

  __shared__ __align__(16) float nbr[KNN][CP];
  __shared__ float cen[C];
  __shared__ int knn[KNN];
  __shared__ float ecen[O];
  __shared__ float red[3][4][O];

  const float* hrow = h + (size_t)bn * hstride;
  if (tid < C) cen[tid] = hrow[tid];
  if (tid < KNN) knn[tid] = idxb[bn * KNN + tid];
  __syncthreads();
  for (int i = tid; i < KNN * C; i += 256) {
    int k = i / C, c = i - k * C;
    nbr[k][c] = h[(size_t)(b * N + knn[k]) * hstride + c];
  }
  if (tid < O) {
    float e = 0.f;
    for (int c = 0; c < C; ++c)
      e += (Wt[(C + c) * O + tid] - Wt[c * O + tid]) * cen[c];
    ecen[tid] = e;
  }
  __syncthreads();

  float acc[32];
#pragma unroll
  for (int i = 0; i < 32; ++i) acc[i] = 0.f;

  const float* wptr = Wt + o0;
  for (int cq = 0; cq < C; cq += 4) {
    const float4 n0 = *reinterpret_cast<const float4*>(&nbr[kbase][cq]);
    const float4 n1 = (KT > 1) ? *reinterpret_cast<const float4*>(&nbr[kbase + 1][cq]) : n0;
    const float4 n2 = (KT > 2) ? *reinterpret_cast<const float4*>(&nbr[kbase + 2][cq]) : n0;
    const float4 n3 = (KT > 3) ? *reinterpret_cast<const float4*>(&nbr[kbase + 3][cq]) : n0;
#define EDGE_CI(comp)                                                      \
    {                                                                      \
      const float4 wa = *reinterpret_cast<const float4*>(wptr);            \
      const float4 wb = *reinterpret_cast<const float4*>(wptr + 4);        \
      acc[0] += wa.x * n0.comp;  acc[1] += wa.y * n0.comp;                 \
      acc[2] += wa.z * n0.comp;  acc[3] += wa.w * n0.comp;                 \
      acc[4] += wb.x * n0.comp;  acc[5] += wb.y * n0.comp;                 \
      acc[6] += wb.z * n0.comp;  acc[7] += wb.w * n0.comp;                 \
      if (KT > 1) {                                                        \
        acc[8] += wa.x * n1.comp;   acc[9] += wa.y * n1.comp;              \
        acc[10] += wa.z * n1.comp;  acc[11] += wa.w * n1.comp;             \
        acc[12] += wb.x * n1.comp;  acc[13] += wb.y * n1.comp;             \
        acc[14] += wb.z * n1.comp;  acc[15] += wb.w * n1.comp;             \
      }                                                                    \
      if (KT > 2) {                                                        \
        acc[16] += wa.x * n2.comp;  acc[17] += wa.y * n2.comp;             \
        acc[18] += wa.z * n2.comp;  acc[19] += wa.w * n2.comp;             \
        acc[20] += wb.x * n2.comp;  acc[21] += wb.y * n2.comp;             \
        acc[22] += wb.z * n2.comp;  acc[23] += wb.w * n2.comp;             \
        acc[24] += wa.x * n3.comp;  acc[25] += wa.y * n3.comp;             \
        acc[26] += wa.z * n3.comp;  acc[27] += wa.w * n3.comp;             \
        acc[28] += wb.x * n3.comp;  acc[29] += wb.y * n3.comp;             \
        acc[30] += wb.z * n3.comp;  acc[31] += wb.w * n3.comp;             \
      }                                                                    \
      wptr += O;                                                           \
    }
    EDGE_CI(x)
    EDGE_CI(y)
    EDGE_CI(z)
    EDGE_CI(w)
#undef EDGE_CI
  }

#pragma unroll
  for (int u = 0; u < 8; ++u) {
    float ec = ecen[o0 + u];
    float e0 = acc[u] + ec;
    float s = e0, q = e0 * e0, m = e0;
    if (KT > 1) {
      float e = acc[8 + u] + ec;
      s += e; q += e * e; m = fmaxf(m, e);
    }
    if (KT > 2) {
      float e = acc[16 + u] + ec;
      s += e; q += e * e; m = fmaxf(m, e);
      e = acc[24 + u] + ec;
      s += e; q += e * e; m = fmaxf(m, e);
    }
#pragma unroll
    for (int msk = OG; msk < 64; msk <<= 1) {
      s += __shfl_xor(s, msk, 64);
      q += __shfl_xor(q, msk, 64);
      m = fmaxf(m, __shfl_xor(m, msk, 64));
    }
    if ((tid & 63) < OG) {
      int wv = tid >> 6;
      red[0][wv][o0 + u] = s;
      red[1][wv][o0 + u] = q;
      red[2][wv][o0 + u] = m;
    }
  }
  __syncthreads();
  if (tid < O) {
    float s = red[0][0][tid] + red[0][1][tid] + red[0][2][tid] + red[0][3][tid];
    float q = red[1][0][tid] + red[1][1][tid] + red[1][2][tid] + red[1][3][tid];
    float m = fmaxf(fmaxf(red[2][0][tid], red[2][1][tid]),
                    fmaxf(red[2][2][tid], red[2][3][tid]));
    atomicAdd(&cstats[(b * O + tid) * 2 + 0], s);
    atomicAdd(&cstats[(b * O + tid) * 2 + 1], q);
    featdst[(size_t)bn * FD + tid] = m;
  }
}

// in-place: featdst = lrelu((featdst - mean) * rsqrt(var + eps))
__global__ void finalize_kernel(const float* __restrict__ cstats,
                                float* __restrict__ featdst, int O) {
  int i = blockIdx.x * 256 + threadIdx.x;
  int o = i % O;
  int bn = i / O;
  int b = bn >> 11;
  float s = cstats[(b * O + o) * 2 + 0];
  float ss = cstats[(b * O + o) * 2 + 1];
  constexpr float inv = 1.f / ((float)N * KNN);
  float m = s * inv;
  float v = fmaxf(ss * inv - m * m, 0.f);
  float* p = &featdst[(size_t)bn * FD + o];
  float e = (*p - m) * rsqrtf(v + EPS);
  *p = lrelu(e);
}

// ---------------------------------------------------------------- 480 -> 128 stage
__global__ __launch_bounds__(256) void fstage_kernel(const float* __restrict__ feats,
                                                     const float* __restrict__ Wht,
                                                     float* __restrict__ fsum,
                                                     float* __restrict__ fss,
                                                     unsigned* __restrict__ fmaxu) {
  int blk = blockIdx.x;
  int b = blk >> 7;
  int n0 = (blk & 127) * 16;
  int tid = threadIdx.x;
  __shared__ float rows[16][FD];
  __shared__ float red[3][2][128];
  for (int i = tid; i < 16 * FD; i += 256) {
    int r = i / FD, c = i - r * FD;
    rows[r][c] = feats[(size_t)(b * N + n0 + r) * FD + c];
  }
  __syncthreads();
  int o = tid & 127, g = tid >> 7;
  float acc[8] = {};
  for (int c = 0; c < FD; ++c) {
    float w = Wht[c * 128 + o];
#pragma unroll
    for (int j = 0; j < 8; ++j) acc[j] += w * rows[g * 8 + j][c];
  }
  float s = 0.f, ss = 0.f, mx = -3.4e38f;
#pragma unroll
  for (int j = 0; j < 8; ++j) {
    float f = acc[j];
    s += f;
    ss += f * f;
    mx = fmaxf(mx, f);
  }
  red[0][g][o] = s;
  red[1][g][o] = ss;
  red[2][g][o] = mx;
  __syncthreads();
  if (g == 0) {
    s += red[0][1][o];
    ss += red[1][1][o];
    mx = fmaxf(mx, red[2][1][o]);
    atomicAdd(&fsum[b * 128 + o], s);
    atomicAdd(&fss[b * 128 + o], ss);
    unsigned u = __float_as_uint(mx);
    u = (u & 0x80000000u) ? ~u : (u | 0x80000000u);
    atomicMax(&fmaxu[b * 128 + o], u);
  }
}

// ---------------------------------------------------------------- head
__global__ __launch_bounds__(128) void head_kernel(const float* __restrict__ fsum,
                                                   const float* __restrict__ fss,
                                                   const unsigned* __restrict__ fmaxu,
                                                   const float* __restrict__ fc1w,
                                                   const float* __restrict__ fc1b,
                                                   const float* __restrict__ fc2w,
                                                   const float* __restrict__ fc2b,
                                                   void* __restrict__ out,
                                                   const int* __restrict__ flag) {
  int b = blockIdx.x, o = threadIdx.x;
  __shared__ float gs[128], t1[128], ys[128];
  constexpr float invN = 1.f / N;
  float m = fsum[b * 128 + o] * invN;
  float v = fmaxf(fss[b * 128 + o] * invN - m * m, 0.f);
  unsigned u = fmaxu[b * 128 + o];
  unsigned bits = (u & 0x80000000u) ? (u ^ 0x80000000u) : ~u;
  float fx = __uint_as_float(bits);
  gs[o] = lrelu((fx - m) * rsqrtf(v + EPS));
  __syncthreads();
  float a = fc1b[o];
  for (int c = 0; c < 128; ++c) a += fc1w[o * 128 + c] * gs[c];
  t1[o] = a;
  __syncthreads();
  float mm = 0.f;
  for (int c = 0; c < 128; ++c) mm += t1[c];
  mm *= (1.f / 128);
  float vv = 0.f;
  for (int c = 0; c < 128; ++c) {
    float d = t1[c] - mm;
    vv += d * d;
  }
  vv *= (1.f / 128);
  ys[o] = lrelu((a - mm) * rsqrtf(vv + EPS));
  __syncthreads();
  float r = fc2b[o];
  for (int c = 0; c < 128; ++c) r += fc2w[o * 128 + c] * ys[c];
  if (flag[0])
    ((float*)out)[b * 128 + o] = r;
  else
    ((bf16*)out)[b * 128 + o] = __float2bfloat16(r);
}

// ---------------------------------------------------------------- driver
template <int C, int O>
static void run_layer(const float* h, int hstride, float* featdst, const float* Wt,
                      float* cstats, float* dist, int* idxb, hipStream_t stream) {
  dist_kernel<C><<<dim3(N / 128, N / 128, B), 256, 0, stream>>>(h, hstride, dist);
  select_kernel<<<B * N / 4, 256, 0, stream>>>(dist, idxb);
  if constexpr (C % 4 == 0 && O >= 64)
    edge_tiled_kernel<C, O><<<B * N, 256, 0, stream>>>(h, hstride, idxb, Wt, cstats, featdst);
  else
    edge_small_kernel<C, O><<<B * N, 256, 0, stream>>>(h, hstride, idxb, Wt, cstats, featdst);
  finalize_kernel<<<B * N * O / 256, 256, 0, stream>>>(cstats, featdst, O);
}

extern "C" void kernel_launch(void* const* d_in, const int* in_sizes, int n_in,
                              void* d_out, int out_size, void* d_ws, size_t ws_size,
                              hipStream_t stream) {
  float* ws = (float*)d_ws;
  float* xf = ws + O_XF;
  float* feats = ws + O_FEATS;
  float* dist = ws + O_DIST;
  int* idxb = (int*)(ws + O_IDX);
  int* flag = (int*)(ws + O_FLAG);

  prep_kernel<<<(PREP_TOTAL + 255) / 256, 256, 0, stream>>>(
      d_in[0], d_in[2], d_in[3], d_in[4], d_in[5], d_in[6], d_in[7], d_in[8], d_in[9],
      d_in[10], ws);

  run_layer<3, 32>(xf, 3, feats + 0, ws + O_WT0, ws + O_CS0, dist, idxb, stream);
  run_layer<32, 64>(feats + 0, FD, feats + 32, ws + O_WT1, ws + O_CS1, dist, idxb, stream);
  run_layer<64, 128>(feats + 32, FD, feats + 96, ws + O_WT2, ws + O_CS2, dist, idxb, stream);
  run_layer<128, 256>(feats + 96, FD, feats + 224, ws + O_WT3, ws + O_CS3, dist, idxb, stream);

  fstage_kernel<<<B * 128, 256, 0, stream>>>(feats, ws + O_WHT, ws + O_FSUM, ws + O_FSS,
                                             (unsigned*)(ws + O_FMAX));
  head_kernel<<<B, 128, 0, stream>>>(ws + O_FSUM, ws + O_FSS, (unsigned*)(ws + O_FMAX),
                                     ws + O_F1W, ws + O_F1B, ws + O_F2W, ws + O_F2B, d_out,
                                     flag);
}

// Round 10
// 1675.760 us; speedup vs baseline: 1.2996x; 1.2996x over previous
//
#include <hip/hip_runtime.h>
#include <hip/hip_bf16.h>
#include <cstdint>

using bf16 = __hip_bfloat16;

static constexpr int B = 2;
static constexpr int N = 2048;
static constexpr int KNN = 32;
static constexpr int FD = 480;
static constexpr float EPS = 1e-5f;
static constexpr float SLOPE = 0.2f;

// ---------------- workspace layout (floats), all compile-time ----------------
static constexpr size_t N_XF = (size_t)B * N * 3;
static constexpr size_t N_FEATS = (size_t)B * N * FD;
static constexpr size_t N_DIST = (size_t)B * N * N;   // also reused as proj [BN][2O]
static constexpr size_t N_IDX = (size_t)B * N * KNN;
static constexpr size_t O_XF = 0;
static constexpr size_t O_FEATS = O_XF + N_XF;
static constexpr size_t O_DIST = O_FEATS + N_FEATS;
static constexpr size_t O_IDX = O_DIST + N_DIST;
static constexpr size_t O_WP0 = O_IDX + N_IDX;        // [3][64]
static constexpr size_t O_WP1 = O_WP0 + 192;          // [32][128]
static constexpr size_t O_WP2 = O_WP1 + 4096;         // [64][256]
static constexpr size_t O_WP3 = O_WP2 + 16384;        // [128][512]
static constexpr size_t O_WHT = O_WP3 + 65536;
static constexpr size_t O_F1W = O_WHT + 61440;
static constexpr size_t O_F1B = O_F1W + 16384;
static constexpr size_t O_F2W = O_F1B + 128;
static constexpr size_t O_F2B = O_F2W + 16384;
static constexpr size_t O_FLAG = O_F2B + 128;
static constexpr size_t O_CS0 = O_FLAG + 16;   // zero region starts here
static constexpr size_t O_CS1 = O_CS0 + 128;
static constexpr size_t O_CS2 = O_CS1 + 256;
static constexpr size_t O_CS3 = O_CS2 + 512;
static constexpr size_t O_FSUM = O_CS3 + 1024;
static constexpr size_t O_FSS = O_FSUM + 256;
static constexpr size_t O_FMAX = O_FSS + 256;
static constexpr size_t O_END = O_FMAX + 256;
static constexpr size_t N_ZERO = O_END - O_CS0;

__device__ __forceinline__ float lrelu(float x) { return x >= 0.f ? x : SLOPE * x; }

__device__ __forceinline__ float load_in(const void* p, int i, int isf32) {
  return isf32 ? ((const float*)p)[i] : __bfloat162float(((const bf16*)p)[i]);
}

// ---------------------------------------------------------------- prep (fused)
// Edge-layer weights are stored projected: Wproj[c][o] = Wd[o][c] (o<O),
// Wproj[c][O+o] = Wc[o][c] - Wd[o][c]. Then edge e[n,k,o] =
// (h[j_k]·Wproj)[o] + (h[n]·Wproj)[O+o] — 1x1 conv distributes over concat.
static constexpr int PREP_TOTAL =
    (int)(N_XF + 96 + 2048 + 8192 + 32768 + 61440 + 16384 + 128 + 16384 + 128 + N_ZERO);

__global__ __launch_bounds__(256) void prep_kernel(
    const void* __restrict__ x, const void* __restrict__ W0, const void* __restrict__ W1,
    const void* __restrict__ W2, const void* __restrict__ W3, const void* __restrict__ Wh,
    const void* __restrict__ fc1w, const void* __restrict__ fc1b,
    const void* __restrict__ fc2w, const void* __restrict__ fc2b, float* __restrict__ ws) {
  __shared__ float red[256];
  const unsigned short* xr = (const unsigned short*)x;
  float mx = 0.f;
  for (int i = threadIdx.x; i < B * N * 3; i += 256) {
    float v = __uint_as_float(((unsigned)xr[i]) << 16);
    v = fabsf(v);
    if (!(v < 1e30f)) v = 1e30f;  // NaN/inf -> huge
    mx = fmaxf(mx, v);
  }
  red[threadIdx.x] = mx;
  __syncthreads();
  for (int s = 128; s > 0; s >>= 1) {
    if (threadIdx.x < s) red[threadIdx.x] = fmaxf(red[threadIdx.x], red[threadIdx.x + s]);
    __syncthreads();
  }
  int isf = red[0] > 1e3f ? 1 : 0;
  if (blockIdx.x == 0 && threadIdx.x == 0) ((int*)(ws + O_FLAG))[0] = isf;

  int idx = blockIdx.x * 256 + threadIdx.x;
  if (idx < (int)N_XF) { ws[O_XF + idx] = load_in(x, idx, isf); return; }
  idx -= (int)N_XF;
  if (idx < 96) {  // W0: O=32,C=3
    int o = idx / 3, c = idx - o * 3;
    float a = load_in(W0, o * 6 + c, isf);
    float bb = load_in(W0, o * 6 + 3 + c, isf);
    ws[O_WP0 + c * 64 + o] = a;
    ws[O_WP0 + c * 64 + 32 + o] = bb - a;
    return;
  }
  idx -= 96;
  if (idx < 2048) {  // W1: O=64,C=32
    int o = idx >> 5, c = idx & 31;
    float a = load_in(W1, o * 64 + c, isf);
    float bb = load_in(W1, o * 64 + 32 + c, isf);
    ws[O_WP1 + c * 128 + o] = a;
    ws[O_WP1 + c * 128 + 64 + o] = bb - a;
    return;
  }
  idx -= 2048;
  if (idx < 8192) {  // W2: O=128,C=64
    int o = idx >> 6, c = idx & 63;
    float a = load_in(W2, o * 128 + c, isf);
    float bb = load_in(W2, o * 128 + 64 + c, isf);
    ws[O_WP2 + c * 256 + o] = a;
    ws[O_WP2 + c * 256 + 128 + o] = bb - a;
    return;
  }
  idx -= 8192;
  if (idx < 32768) {  // W3: O=256,C=128
    int o = idx >> 7, c = idx & 127;
    float a = load_in(W3, o * 256 + c, isf);
    float bb = load_in(W3, o * 256 + 128 + c, isf);
    ws[O_WP3 + c * 512 + o] = a;
    ws[O_WP3 + c * 512 + 256 + o] = bb - a;
    return;
  }
  idx -= 32768;
  if (idx < 61440) {  // Wh [128][480] -> [480][128]
    int o = idx / 480, c = idx - o * 480;
    ws[O_WHT + c * 128 + o] = load_in(Wh, idx, isf);
    return;
  }
  idx -= 61440;
  if (idx < 16384) { ws[O_F1W + idx] = load_in(fc1w, idx, isf); return; }
  idx -= 16384;
  if (idx < 128) { ws[O_F1B + idx] = load_in(fc1b, idx, isf); return; }
  idx -= 128;
  if (idx < 16384) { ws[O_F2W + idx] = load_in(fc2w, idx, isf); return; }
  idx -= 16384;
  if (idx < 128) { ws[O_F2B + idx] = load_in(fc2b, idx, isf); return; }
  idx -= 128;
  if (idx < (int)N_ZERO) ws[O_CS0 + idx] = 0.f;
}

// ---------------------------------------------------------------- dist (sq fused)
template <int C>
__global__ __launch_bounds__(256) void dist_kernel(const float* __restrict__ h, int hstride,
                                                   float* __restrict__ dist) {
  constexpr int CW = 16;
  __shared__ float Ast[CW][132];
  __shared__ float Bst[CW][132];
  __shared__ float sqn[128], sqm[128];
  int b = blockIdx.z;
  int n0 = blockIdx.y * 128, m0 = blockIdx.x * 128;
  int tid = threadIdx.x;
  int tx = tid & 15, ty = tid >> 4;
  int rr = tid & 127;
  float dot[8][8] = {};
  float sqacc = 0.f;
  for (int cc = 0; cc < C; cc += CW) {
    for (int i = tid; i < 128 * CW; i += 256) {
      int c = i & 15, r = i >> 4;
      int gc = cc + c;
      float av = 0.f, bv = 0.f;
      if (gc < C) {
        av = h[(size_t)(b * N + n0 + r) * hstride + gc];
        bv = h[(size_t)(b * N + m0 + r) * hstride + gc];
      }
      Ast[c][r] = av;
      Bst[c][r] = bv;
    }
    __syncthreads();
    if (tid < 128) {
#pragma unroll
      for (int c = 0; c < CW; ++c) { float v = Ast[c][rr]; sqacc += v * v; }
    } else {
#pragma unroll
      for (int c = 0; c < CW; ++c) { float v = Bst[c][rr]; sqacc += v * v; }
    }
#pragma unroll
    for (int c = 0; c < CW; ++c) {
      float av[8], bv[8];
#pragma unroll
      for (int i = 0; i < 8; ++i) av[i] = Ast[c][ty * 8 + i];
#pragma unroll
      for (int j = 0; j < 8; ++j) bv[j] = Bst[c][tx * 8 + j];
#pragma unroll
      for (int i = 0; i < 8; ++i)
#pragma unroll
        for (int j = 0; j < 8; ++j) dot[i][j] += av[i] * bv[j];
    }
    __syncthreads();
  }
  if (tid < 128) sqn[rr] = sqacc; else sqm[rr] = sqacc;
  __syncthreads();
#pragma unroll
  for (int i = 0; i < 8; ++i) {
    int nn = n0 + ty * 8 + i;
    float sn = sqn[ty * 8 + i];
#pragma unroll
    for (int jq = 0; jq < 2; ++jq) {
      float4 w;
      w.x = sn + sqm[tx * 8 + jq * 4 + 0] - 2.f * dot[i][jq * 4 + 0];
      w.y = sn + sqm[tx * 8 + jq * 4 + 1] - 2.f * dot[i][jq * 4 + 1];
      w.z = sn + sqm[tx * 8 + jq * 4 + 2] - 2.f * dot[i][jq * 4 + 2];
      w.w = sn + sqm[tx * 8 + jq * 4 + 3] - 2.f * dot[i][jq * 4 + 3];
      *reinterpret_cast<float4*>(&dist[(size_t)(b * N + nn) * N + m0 + tx * 8 + jq * 4]) = w;
    }
  }
}

__device__ __forceinline__ unsigned long long wave_min_u64(unsigned long long v) {
#pragma unroll
  for (int m = 1; m < 64; m <<= 1) {
    unsigned lo = (unsigned)v;
    unsigned hi = (unsigned)(v >> 32);
    unsigned olo = (unsigned)__shfl_xor((int)lo, m, 64);
    unsigned ohi = (unsigned)__shfl_xor((int)hi, m, 64);
    unsigned long long ov = ((unsigned long long)ohi << 32) | olo;
    if (ov < v) v = ov;
  }
  return v;
}

__global__ __launch_bounds__(256) void select_kernel(const float* __restrict__ dist,
                                                     int* __restrict__ idxb) {
  int row = blockIdx.x * 4 + (threadIdx.x >> 6);  // b*N + n
  int lane = threadIdx.x & 63;
  const float* drow = dist + (size_t)row * N;
  unsigned long long key[32];
#pragma unroll
  for (int j = 0; j < 32; ++j) {
    int m = j * 64 + lane;
    unsigned u = __float_as_uint(drow[m]);
    u = (u & 0x80000000u) ? ~u : (u | 0x80000000u);
    key[j] = ((unsigned long long)u << 32) | (unsigned)m;
  }
  unsigned long long lmin = key[0];
#pragma unroll
  for (int j = 1; j < 32; ++j) lmin = key[j] < lmin ? key[j] : lmin;
  unsigned saved = 0;
  for (int it = 0; it <= KNN; ++it) {
    unsigned long long gmin = wave_min_u64(lmin);
    if (it > 0 && lane == it - 1) saved = (unsigned)(gmin & 0xFFFFFFFFull);
    if (lmin == gmin) {
#pragma unroll
      for (int j = 0; j < 32; ++j)
        if (key[j] == gmin) key[j] = ~0ull;
      lmin = key[0];
#pragma unroll
      for (int j = 1; j < 32; ++j) lmin = key[j] < lmin ? key[j] : lmin;
    }
  }
  if (lane < KNN) idxb[row * KNN + lane] = (int)saved;
}

// ---------------------------------------------------------------- proj GEMM
// proj[bn][o2] = sum_c h[bn][c] * Wp[c][o2], o2 in [0, 2O). 64x64 block tile,
// 4x4 per thread (R1-proven structure; VGPR-safe).
template <int C, int NO2>
__global__ __launch_bounds__(256) void proj_kernel(const float* __restrict__ h, int hstride,
                                                   const float* __restrict__ Wp,
                                                   float* __restrict__ proj) {
  constexpr int CW = 16;
  __shared__ float As[64][17];
  __shared__ float Bs[64][17];
  int n0 = blockIdx.y * 64;
  int m0 = blockIdx.x * 64;
  int tid = threadIdx.x;
  int tx = tid & 15, ty = tid >> 4;
  float dot[4][4] = {};
  for (int cc = 0; cc < C; cc += CW) {
    for (int i = tid; i < 64 * CW; i += 256) {
      int r = i >> 4, c = i & 15;
      int gc = cc + c;
      As[r][c] = (gc < C) ? h[(size_t)(n0 + r) * hstride + gc] : 0.f;
    }
    for (int i = tid; i < 64 * CW; i += 256) {
      int c = i >> 6, m = i & 63;
      int gc = cc + c;
      Bs[m][c] = (gc < C) ? Wp[(size_t)gc * NO2 + m0 + m] : 0.f;
    }
    __syncthreads();
#pragma unroll
    for (int c = 0; c < CW; ++c) {
      float av[4], bv[4];
#pragma unroll
      for (int i = 0; i < 4; ++i) av[i] = As[ty * 4 + i][c];
#pragma unroll
      for (int j = 0; j < 4; ++j) bv[j] = Bs[tx * 4 + j][c];
#pragma unroll
      for (int i = 0; i < 4; ++i)
#pragma unroll
        for (int j = 0; j < 4; ++j) dot[i][j] += av[i] * bv[j];
    }
    __syncthreads();
  }
#pragma unroll
  for (int i = 0; i < 4; ++i) {
    float4 w;
    w.x = dot[i][0];
    w.y = dot[i][1];
    w.z = dot[i][2];
    w.w = dot[i][3];
    *reinterpret_cast<float4*>(&proj[(size_t)(n0 + ty * 4 + i) * NO2 + m0 + tx * 4]) = w;
  }
}

// ---------------------------------------------------------------- edge reduce
// e[n,k,o] = proj[b*N + knn[n][k]][o] + proj[bn][O+o]. Per (bn,o) thread:
// gather 32 rows, running sum/sumsq/max. Max -> featdst, stats -> atomics.
template <int O>
__global__ __launch_bounds__(256) void edge_reduce_kernel(const float* __restrict__ proj,
                                                          const int* __restrict__ idxb,
                                                          float* __restrict__ cstats,
                                                          float* __restrict__ featdst) {
  constexpr int G = 256 / O;  // bn per block
  constexpr int NO2 = 2 * O;
  __shared__ int knn[G * KNN];
  int bn0 = blockIdx.x * G;
  int tid = threadIdx.x;
  if (tid < G * KNN) knn[tid] = idxb[bn0 * KNN + tid];
  __syncthreads();
  int g = tid / O;
  int o = tid - g * O;
  int bn = bn0 + g;
  int b = bn >> 11;
  int jbase = b << 11;  // knn indices are within-batch; proj rows are global bn
  float h0 = proj[(size_t)bn * NO2 + O + o];
  float s = 0.f, ss = 0.f, m = -3.4e38f;
#pragma unroll 4
  for (int k = 0; k < KNN; ++k) {
    int j = jbase + knn[g * KNN + k];
    float e = proj[(size_t)j * NO2 + o] + h0;
    s += e;
    ss += e * e;
    m = fmaxf(m, e);
  }
  featdst[(size_t)bn * FD + o] = m;
  atomicAdd(&cstats[(b * O + o) * 2 + 0], s);
  atomicAdd(&cstats[(b * O + o) * 2 + 1], ss);
}

// in-place: featdst = lrelu((featdst - mean) * rsqrt(var + eps))
__global__ void finalize_kernel(const float* __restrict__ cstats,
                                float* __restrict__ featdst, int O) {
  int i = blockIdx.x * 256 + threadIdx.x;
  int o = i % O;
  int bn = i / O;
  int b = bn >> 11;
  float s = cstats[(b * O + o) * 2 + 0];
  float ss = cstats[(b * O + o) * 2 + 1];
  constexpr float inv = 1.f / ((float)N * KNN);
  float m = s * inv;
  float v = fmaxf(ss * inv - m * m, 0.f);
  float* p = &featdst[(size_t)bn * FD + o];
  float e = (*p - m) * rsqrtf(v + EPS);
  *p = lrelu(e);
}

// ---------------------------------------------------------------- 480 -> 128 stage
__global__ __launch_bounds__(256) void fstage_kernel(const float* __restrict__ feats,
                                                     const float* __restrict__ Wht,
                                                     float* __restrict__ fsum,
                                                     float* __restrict__ fss,
                                                     unsigned* __restrict__ fmaxu) {
  int blk = blockIdx.x;
  int b = blk >> 7;
  int n0 = (blk & 127) * 16;
  int tid = threadIdx.x;
  __shared__ float rows[16][FD];
  __shared__ float red[3][2][128];
  for (int i = tid; i < 16 * FD; i += 256) {
    int r = i / FD, c = i - r * FD;
    rows[r][c] = feats[(size_t)(b * N + n0 + r) * FD + c];
  }
  __syncthreads();
  int o = tid & 127, g = tid >> 7;
  float acc[8] = {};
  for (int c = 0; c < FD; ++c) {
    float w = Wht[c * 128 + o];
#pragma unroll
    for (int j = 0; j < 8; ++j) acc[j] += w * rows[g * 8 + j][c];
  }
  float s = 0.f, ss = 0.f, mx = -3.4e38f;
#pragma unroll
  for (int j = 0; j < 8; ++j) {
    float f = acc[j];
    s += f;
    ss += f * f;
    mx = fmaxf(mx, f);
  }
  red[0][g][o] = s;
  red[1][g][o] = ss;
  red[2][g][o] = mx;
  __syncthreads();
  if (g == 0) {
    s += red[0][1][o];
    ss += red[1][1][o];
    mx = fmaxf(mx, red[2][1][o]);
    atomicAdd(&fsum[b * 128 + o], s);
    atomicAdd(&fss[b * 128 + o], ss);
    unsigned u = __float_as_uint(mx);
    u = (u & 0x80000000u) ? ~u : (u | 0x80000000u);
    atomicMax(&fmaxu[b * 128 + o], u);
  }
}

// ---------------------------------------------------------------- head
__global__ __launch_bounds__(128) void head_kernel(const float* __restrict__ fsum,
                                                   const float* __restrict__ fss,
                                                   const unsigned* __restrict__ fmaxu,
                                                   const float* __restrict__ fc1w,
                                                   const float* __restrict__ fc1b,
                                                   const float* __restrict__ fc2w,
                                                   const float* __restrict__ fc2b,
                                                   void* __restrict__ out,
                                                   const int* __restrict__ flag) {
  int b = blockIdx.x, o = threadIdx.x;
  __shared__ float gs[128], t1[128], ys[128];
  constexpr float invN = 1.f / N;
  float m = fsum[b * 128 + o] * invN;
  float v = fmaxf(fss[b * 128 + o] * invN - m * m, 0.f);
  unsigned u = fmaxu[b * 128 + o];
  unsigned bits = (u & 0x80000000u) ? (u ^ 0x80000000u) : ~u;
  float fx = __uint_as_float(bits);
  gs[o] = lrelu((fx - m) * rsqrtf(v + EPS));
  __syncthreads();
  float a = fc1b[o];
  for (int c = 0; c < 128; ++c) a += fc1w[o * 128 + c] * gs[c];
  t1[o] = a;
  __syncthreads();
  float mm = 0.f;
  for (int c = 0; c < 128; ++c) mm += t1[c];
  mm *= (1.f / 128);
  float vv = 0.f;
  for (int c = 0; c < 128; ++c) {
    float d = t1[c] - mm;
    vv += d * d;
  }
  vv *= (1.f / 128);
  ys[o] = lrelu((a - mm) * rsqrtf(vv + EPS));
  __syncthreads();
  float r = fc2b[o];
  for (int c = 0; c < 128; ++c) r += fc2w[o * 128 + c] * ys[c];
  if (flag[0])
    ((float*)out)[b * 128 + o] = r;
  else
    ((bf16*)out)[b * 128 + o] = __float2bfloat16(r);
}

// ---------------------------------------------------------------- driver
template <int C, int O>
static void run_layer(const float* h, int hstride, float* featdst, const float* Wp,
                      float* cstats, float* distproj, int* idxb, hipStream_t stream) {
  dist_kernel<C><<<dim3(N / 128, N / 128, B), 256, 0, stream>>>(h, hstride, distproj);
  select_kernel<<<B * N / 4, 256, 0, stream>>>(distproj, idxb);
  // dist is dead after select; reuse the buffer for proj [BN][2O]
  proj_kernel<C, 2 * O><<<dim3(2 * O / 64, B * N / 64), 256, 0, stream>>>(h, hstride, Wp,
                                                                          distproj);
  edge_reduce_kernel<O><<<B * N / (256 / O), 256, 0, stream>>>(distproj, idxb, cstats,
                                                               featdst);
  finalize_kernel<<<B * N * O / 256, 256, 0, stream>>>(cstats, featdst, O);
}

extern "C" void kernel_launch(void* const* d_in, const int* in_sizes, int n_in,
                              void* d_out, int out_size, void* d_ws, size_t ws_size,
                              hipStream_t stream) {
  float* ws = (float*)d_ws;
  float* xf = ws + O_XF;
  float* feats = ws + O_FEATS;
  float* distproj = ws + O_DIST;
  int* idxb = (int*)(ws + O_IDX);
  int* flag = (int*)(ws + O_FLAG);

  prep_kernel<<<(PREP_TOTAL + 255) / 256, 256, 0, stream>>>(
      d_in[0], d_in[2], d_in[3], d_in[4], d_in[5], d_in[6], d_in[7], d_in[8], d_in[9],
      d_in[10], ws);

  run_layer<3, 32>(xf, 3, feats + 0, ws + O_WP0, ws + O_CS0, distproj, idxb, stream);
  run_layer<32, 64>(feats + 0, FD, feats + 32, ws + O_WP1, ws + O_CS1, distproj, idxb, stream);
  run_layer<64, 128>(feats + 32, FD, feats + 96, ws + O_WP2, ws + O_CS2, distproj, idxb,
                     stream);
  run_layer<128, 256>(feats + 96, FD, feats + 224, ws + O_WP3, ws + O_CS3, distproj, idxb,
                      stream);

  fstage_kernel<<<B * 128, 256, 0, stream>>>(feats, ws + O_WHT, ws + O_FSUM, ws + O_FSS,
                                             (unsigned*)(ws + O_FMAX));
  head_kernel<<<B, 128, 0, stream>>>(ws + O_FSUM, ws + O_FSS, (unsigned*)(ws + O_FMAX),
                                     ws + O_F1W, ws + O_F1B, ws + O_F2W, ws + O_F2B, d_out,
                                     flag);
}

// Round 11
// 1104.746 us; speedup vs baseline: 1.9713x; 1.5169x over previous
//
#include <hip/hip_runtime.h>
#include <hip/hip_bf16.h>
#include <cstdint>

using bf16 = __hip_bfloat16;

static constexpr int B = 2;
static constexpr int N = 2048;
static constexpr int KNN = 32;
static constexpr int FD = 480;
static constexpr float EPS = 1e-5f;
static constexpr float SLOPE = 0.2f;

// ---------------- workspace layout (floats), all compile-time ----------------
static constexpr size_t N_XF = (size_t)B * N * 3;
static constexpr size_t N_FEATS = (size_t)B * N * FD;
static constexpr size_t N_DIST = (size_t)B * N * N;   // also reused as proj [BN][2O]
static constexpr size_t N_IDX = (size_t)B * N * KNN;
static constexpr size_t O_XF = 0;
static constexpr size_t O_FEATS = O_XF + N_XF;
static constexpr size_t O_DIST = O_FEATS + N_FEATS;
static constexpr size_t O_IDX = O_DIST + N_DIST;
static constexpr size_t O_WP0 = O_IDX + N_IDX;        // [3][64]
static constexpr size_t O_WP1 = O_WP0 + 192;          // [32][128]
static constexpr size_t O_WP2 = O_WP1 + 4096;         // [64][256]
static constexpr size_t O_WP3 = O_WP2 + 16384;        // [128][512]
static constexpr size_t O_WHT = O_WP3 + 65536;
static constexpr size_t O_F1W = O_WHT + 61440;
static constexpr size_t O_F1B = O_F1W + 16384;
static constexpr size_t O_F2W = O_F1B + 128;
static constexpr size_t O_F2B = O_F2W + 16384;
static constexpr size_t O_FLAG = O_F2B + 128;
static constexpr size_t O_CS0 = O_FLAG + 16;   // zero region starts here
static constexpr size_t O_CS1 = O_CS0 + 128;
static constexpr size_t O_CS2 = O_CS1 + 256;
static constexpr size_t O_CS3 = O_CS2 + 512;
static constexpr size_t O_FSUM = O_CS3 + 1024;
static constexpr size_t O_FSS = O_FSUM + 256;
static constexpr size_t O_FMAX = O_FSS + 256;
static constexpr size_t O_END = O_FMAX + 256;
static constexpr size_t N_ZERO = O_END - O_CS0;

__device__ __forceinline__ float lrelu(float x) { return x >= 0.f ? x : SLOPE * x; }

__device__ __forceinline__ float load_in(const void* p, int i, int isf32) {
  return isf32 ? ((const float*)p)[i] : __bfloat162float(((const bf16*)p)[i]);
}

// ---------------------------------------------------------------- prep (fused)
// Edge-layer weights are stored projected: Wproj[c][o] = Wd[o][c] (o<O),
// Wproj[c][O+o] = Wc[o][c] - Wd[o][c]. Then edge e[n,k,o] =
// (h[j_k]·Wproj)[o] + (h[n]·Wproj)[O+o] — 1x1 conv distributes over concat.
static constexpr int PREP_TOTAL =
    (int)(N_XF + 96 + 2048 + 8192 + 32768 + 61440 + 16384 + 128 + 16384 + 128 + N_ZERO);

__global__ __launch_bounds__(256) void prep_kernel(
    const void* __restrict__ x, const void* __restrict__ W0, const void* __restrict__ W1,
    const void* __restrict__ W2, const void* __restrict__ W3, const void* __restrict__ Wh,
    const void* __restrict__ fc1w, const void* __restrict__ fc1b,
    const void* __restrict__ fc2w, const void* __restrict__ fc2b, float* __restrict__ ws) {
  __shared__ float red[256];
  const unsigned short* xr = (const unsigned short*)x;
  float mx = 0.f;
  for (int i = threadIdx.x; i < B * N * 3; i += 256) {
    float v = __uint_as_float(((unsigned)xr[i]) << 16);
    v = fabsf(v);
    if (!(v < 1e30f)) v = 1e30f;  // NaN/inf -> huge
    mx = fmaxf(mx, v);
  }
  red[threadIdx.x] = mx;
  __syncthreads();
  for (int s = 128; s > 0; s >>= 1) {
    if (threadIdx.x < s) red[threadIdx.x] = fmaxf(red[threadIdx.x], red[threadIdx.x + s]);
    __syncthreads();
  }
  int isf = red[0] > 1e3f ? 1 : 0;
  if (blockIdx.x == 0 && threadIdx.x == 0) ((int*)(ws + O_FLAG))[0] = isf;

  int idx = blockIdx.x * 256 + threadIdx.x;
  if (idx < (int)N_XF) { ws[O_XF + idx] = load_in(x, idx, isf); return; }
  idx -= (int)N_XF;
  if (idx < 96) {  // W0: O=32,C=3
    int o = idx / 3, c = idx - o * 3;
    float a = load_in(W0, o * 6 + c, isf);
    float bb = load_in(W0, o * 6 + 3 + c, isf);
    ws[O_WP0 + c * 64 + o] = a;
    ws[O_WP0 + c * 64 + 32 + o] = bb - a;
    return;
  }
  idx -= 96;
  if (idx < 2048) {  // W1: O=64,C=32
    int o = idx >> 5, c = idx & 31;
    float a = load_in(W1, o * 64 + c, isf);
    float bb = load_in(W1, o * 64 + 32 + c, isf);
    ws[O_WP1 + c * 128 + o] = a;
    ws[O_WP1 + c * 128 + 64 + o] = bb - a;
    return;
  }
  idx -= 2048;
  if (idx < 8192) {  // W2: O=128,C=64
    int o = idx >> 6, c = idx & 63;
    float a = load_in(W2, o * 128 + c, isf);
    float bb = load_in(W2, o * 128 + 64 + c, isf);
    ws[O_WP2 + c * 256 + o] = a;
    ws[O_WP2 + c * 256 + 128 + o] = bb - a;
    return;
  }
  idx -= 8192;
  if (idx < 32768) {  // W3: O=256,C=128
    int o = idx >> 7, c = idx & 127;
    float a = load_in(W3, o * 256 + c, isf);
    float bb = load_in(W3, o * 256 + 128 + c, isf);
    ws[O_WP3 + c * 512 + o] = a;
    ws[O_WP3 + c * 512 + 256 + o] = bb - a;
    return;
  }
  idx -= 32768;
  if (idx < 61440) {  // Wh [128][480] -> [480][128]
    int o = idx / 480, c = idx - o * 480;
    ws[O_WHT + c * 128 + o] = load_in(Wh, idx, isf);
    return;
  }
  idx -= 61440;
  if (idx < 16384) { ws[O_F1W + idx] = load_in(fc1w, idx, isf); return; }
  idx -= 16384;
  if (idx < 128) { ws[O_F1B + idx] = load_in(fc1b, idx, isf); return; }
  idx -= 128;
  if (idx < 16384) { ws[O_F2W + idx] = load_in(fc2w, idx, isf); return; }
  idx -= 16384;
  if (idx < 128) { ws[O_F2B + idx] = load_in(fc2b, idx, isf); return; }
  idx -= 128;
  if (idx < (int)N_ZERO) ws[O_CS0 + idx] = 0.f;
}

// ---------------------------------------------------------------- dist (sq fused)
template <int C>
__global__ __launch_bounds__(256) void dist_kernel(const float* __restrict__ h, int hstride,
                                                   float* __restrict__ dist) {
  constexpr int CW = 16;
  __shared__ float Ast[CW][132];
  __shared__ float Bst[CW][132];
  __shared__ float sqn[128], sqm[128];
  int b = blockIdx.z;
  int n0 = blockIdx.y * 128, m0 = blockIdx.x * 128;
  int tid = threadIdx.x;
  int tx = tid & 15, ty = tid >> 4;
  int rr = tid & 127;
  float dot[8][8] = {};
  float sqacc = 0.f;
  for (int cc = 0; cc < C; cc += CW) {
    for (int i = tid; i < 128 * CW; i += 256) {
      int c = i & 15, r = i >> 4;
      int gc = cc + c;
      float av = 0.f, bv = 0.f;
      if (gc < C) {
        av = h[(size_t)(b * N + n0 + r) * hstride + gc];
        bv = h[(size_t)(b * N + m0 + r) * hstride + gc];
      }
      Ast[c][r] = av;
      Bst[c][r] = bv;
    }
    __syncthreads();
    if (tid < 128) {
#pragma unroll
      for (int c = 0; c < CW; ++c) { float v = Ast[c][rr]; sqacc += v * v; }
    } else {
#pragma unroll
      for (int c = 0; c < CW; ++c) { float v = Bst[c][rr]; sqacc += v * v; }
    }
#pragma unroll
    for (int c = 0; c < CW; ++c) {
      float av[8], bv[8];
#pragma unroll
      for (int i = 0; i < 8; ++i) av[i] = Ast[c][ty * 8 + i];
#pragma unroll
      for (int j = 0; j < 8; ++j) bv[j] = Bst[c][tx * 8 + j];
#pragma unroll
      for (int i = 0; i < 8; ++i)
#pragma unroll
        for (int j = 0; j < 8; ++j) dot[i][j] += av[i] * bv[j];
    }
    __syncthreads();
  }
  if (tid < 128) sqn[rr] = sqacc; else sqm[rr] = sqacc;
  __syncthreads();
#pragma unroll
  for (int i = 0; i < 8; ++i) {
    int nn = n0 + ty * 8 + i;
    float sn = sqn[ty * 8 + i];
#pragma unroll
    for (int jq = 0; jq < 2; ++jq) {
      float4 w;
      w.x = sn + sqm[tx * 8 + jq * 4 + 0] - 2.f * dot[i][jq * 4 + 0];
      w.y = sn + sqm[tx * 8 + jq * 4 + 1] - 2.f * dot[i][jq * 4 + 1];
      w.z = sn + sqm[tx * 8 + jq * 4 + 2] - 2.f * dot[i][jq * 4 + 2];
      w.w = sn + sqm[tx * 8 + jq * 4 + 3] - 2.f * dot[i][jq * 4 + 3];
      *reinterpret_cast<float4*>(&dist[(size_t)(b * N + nn) * N + m0 + tx * 8 + jq * 4]) = w;
    }
  }
}

__device__ __forceinline__ unsigned long long wave_min_u64(unsigned long long v) {
#pragma unroll
  for (int m = 1; m < 64; m <<= 1) {
    unsigned lo = (unsigned)v;
    unsigned hi = (unsigned)(v >> 32);
    unsigned olo = (unsigned)__shfl_xor((int)lo, m, 64);
    unsigned ohi = (unsigned)__shfl_xor((int)hi, m, 64);
    unsigned long long ov = ((unsigned long long)ohi << 32) | olo;
    if (ov < v) v = ov;
  }
  return v;
}

// One wave per row. State = 32 u32 ordered-distance bits per lane (32 VGPRs,
// stays register-resident — the R10 u64 version at 64 VGPRs was rematerialized
// from memory by the compiler, serializing every rescan). Column index is
// implicit (m = j*64+lane); the u64 tie-break key (dist<<32|m) is composed
// on the fly. Winner-lane clear uses an unrolled constant-index compare loop
// (no dynamic register indexing — spill rule from R5/R6/R8).
__global__ __launch_bounds__(256) void select_kernel(const float* __restrict__ dist,
                                                     int* __restrict__ idxb) {
  int row = blockIdx.x * 4 + (threadIdx.x >> 6);  // b*N + n
  int lane = threadIdx.x & 63;
  const float* drow = dist + (size_t)row * N;
  unsigned dk[32];
#pragma unroll
  for (int j = 0; j < 32; ++j) {
    unsigned u = __float_as_uint(drow[j * 64 + lane]);
    dk[j] = (u & 0x80000000u) ? ~u : (u | 0x80000000u);
  }
  unsigned ld = dk[0];
  int lj = 0;
#pragma unroll
  for (int j = 1; j < 32; ++j) {
    if (dk[j] < ld) { ld = dk[j]; lj = j; }
  }
  unsigned saved = 0;
  for (int it = 0; it <= KNN; ++it) {
    unsigned long long lkey =
        ((unsigned long long)ld << 32) | (unsigned)(lj * 64 + lane);
    unsigned long long g = wave_min_u64(lkey);
    if (it > 0 && lane == it - 1) saved = (unsigned)(g & 0xFFFFFFFFull);
    if (lkey == g) {  // unique m per lane -> exactly one winner
#pragma unroll
      for (int j = 0; j < 32; ++j)
        if (j == lj) dk[j] = 0xFFFFFFFFu;
      ld = dk[0];
      lj = 0;
#pragma unroll
      for (int j = 1; j < 32; ++j) {
        if (dk[j] < ld) { ld = dk[j]; lj = j; }
      }
    }
  }
  if (lane < KNN) idxb[row * KNN + lane] = (int)saved;
}

// ---------------------------------------------------------------- proj GEMM
// proj[bn][o2] = sum_c h[bn][c] * Wp[c][o2], o2 in [0, 2O). 64x64 block tile,
// 4x4 per thread (R1-proven structure; VGPR-safe).
template <int C, int NO2>
__global__ __launch_bounds__(256) void proj_kernel(const float* __restrict__ h, int hstride,
                                                   const float* __restrict__ Wp,
                                                   float* __restrict__ proj) {
  constexpr int CW = 16;
  __shared__ float As[64][17];
  __shared__ float Bs[64][17];
  int n0 = blockIdx.y * 64;
  int m0 = blockIdx.x * 64;
  int tid = threadIdx.x;
  int tx = tid & 15, ty = tid >> 4;
  float dot[4][4] = {};
  for (int cc = 0; cc < C; cc += CW) {
    for (int i = tid; i < 64 * CW; i += 256) {
      int r = i >> 4, c = i & 15;
      int gc = cc + c;
      As[r][c] = (gc < C) ? h[(size_t)(n0 + r) * hstride + gc] : 0.f;
    }
    for (int i = tid; i < 64 * CW; i += 256) {
      int c = i >> 6, m = i & 63;
      int gc = cc + c;
      Bs[m][c] = (gc < C) ? Wp[(size_t)gc * NO2 + m0 + m] : 0.f;
    }
    __syncthreads();
#pragma unroll
    for (int c = 0; c < CW; ++c) {
      float av[4], bv[4];
#pragma unroll
      for (int i = 0; i < 4; ++i) av[i] = As[ty * 4 + i][c];
#pragma unroll
      for (int j = 0; j < 4; ++j) bv[j] = Bs[tx * 4 + j][c];
#pragma unroll
      for (int i = 0; i < 4; ++i)
#pragma unroll
        for (int j = 0; j < 4; ++j) dot[i][j] += av[i] * bv[j];
    }
    __syncthreads();
  }
#pragma unroll
  for (int i = 0; i < 4; ++i) {
    float4 w;
    w.x = dot[i][0];
    w.y = dot[i][1];
    w.z = dot[i][2];
    w.w = dot[i][3];
    *reinterpret_cast<float4*>(&proj[(size_t)(n0 + ty * 4 + i) * NO2 + m0 + tx * 4]) = w;
  }
}

// ---------------------------------------------------------------- edge reduce
// e[n,k,o] = proj[b*N + knn[n][k]][o] + proj[bn][O+o]. Per (bn,o) thread:
// gather 32 rows, running sum/sumsq/max. Max -> featdst, stats -> atomics.
template <int O>
__global__ __launch_bounds__(256) void edge_reduce_kernel(const float* __restrict__ proj,
                                                          const int* __restrict__ idxb,
                                                          float* __restrict__ cstats,
                                                          float* __restrict__ featdst) {
  constexpr int G = 256 / O;  // bn per block
  constexpr int NO2 = 2 * O;
  __shared__ int knn[G * KNN];
  int bn0 = blockIdx.x * G;
  int tid = threadIdx.x;
  if (tid < G * KNN) knn[tid] = idxb[bn0 * KNN + tid];
  __syncthreads();
  int g = tid / O;
  int o = tid - g * O;
  int bn = bn0 + g;
  int b = bn >> 11;
  int jbase = b << 11;  // knn indices are within-batch; proj rows are global bn
  float h0 = proj[(size_t)bn * NO2 + O + o];
  float s = 0.f, ss = 0.f, m = -3.4e38f;
#pragma unroll 4
  for (int k = 0; k < KNN; ++k) {
    int j = jbase + knn[g * KNN + k];
    float e = proj[(size_t)j * NO2 + o] + h0;
    s += e;
    ss += e * e;
    m = fmaxf(m, e);
  }
  featdst[(size_t)bn * FD + o] = m;
  atomicAdd(&cstats[(b * O + o) * 2 + 0], s);
  atomicAdd(&cstats[(b * O + o) * 2 + 1], ss);
}

// in-place: featdst = lrelu((featdst - mean) * rsqrt(var + eps))
__global__ void finalize_kernel(const float* __restrict__ cstats,
                                float* __restrict__ featdst, int O) {
  int i = blockIdx.x * 256 + threadIdx.x;
  int o = i % O;
  int bn = i / O;
  int b = bn >> 11;
  float s = cstats[(b * O + o) * 2 + 0];
  float ss = cstats[(b * O + o) * 2 + 1];
  constexpr float inv = 1.f / ((float)N * KNN);
  float m = s * inv;
  float v = fmaxf(ss * inv - m * m, 0.f);
  float* p = &featdst[(size_t)bn * FD + o];
  float e = (*p - m) * rsqrtf(v + EPS);
  *p = lrelu(e);
}

// ---------------------------------------------------------------- 480 -> 128 stage
__global__ __launch_bounds__(256) void fstage_kernel(const float* __restrict__ feats,
                                                     const float* __restrict__ Wht,
                                                     float* __restrict__ fsum,
                                                     float* __restrict__ fss,
                                                     unsigned* __restrict__ fmaxu) {
  int blk = blockIdx.x;
  int b = blk >> 7;
  int n0 = (blk & 127) * 16;
  int tid = threadIdx.x;
  __shared__ float rows[16][FD];
  __shared__ float red[3][2][128];
  for (int i = tid; i < 16 * FD; i += 256) {
    int r = i / FD, c = i - r * FD;
    rows[r][c] = feats[(size_t)(b * N + n0 + r) * FD + c];
  }
  __syncthreads();
  int o = tid & 127, g = tid >> 7;
  float acc[8] = {};
  for (int c = 0; c < FD; ++c) {
    float w = Wht[c * 128 + o];
#pragma unroll
    for (int j = 0; j < 8; ++j) acc[j] += w * rows[g * 8 + j][c];
  }
  float s = 0.f, ss = 0.f, mx = -3.4e38f;
#pragma unroll
  for (int j = 0; j < 8; ++j) {
    float f = acc[j];
    s += f;
    ss += f * f;
    mx = fmaxf(mx, f);
  }
  red[0][g][o] = s;
  red[1][g][o] = ss;
  red[2][g][o] = mx;
  __syncthreads();
  if (g == 0) {
    s += red[0][1][o];
    ss += red[1][1][o];
    mx = fmaxf(mx, red[2][1][o]);
    atomicAdd(&fsum[b * 128 + o], s);
    atomicAdd(&fss[b * 128 + o], ss);
    unsigned u = __float_as_uint(mx);
    u = (u & 0x80000000u) ? ~u : (u | 0x80000000u);
    atomicMax(&fmaxu[b * 128 + o], u);
  }
}

// ---------------------------------------------------------------- head
__global__ __launch_bounds__(128) void head_kernel(const float* __restrict__ fsum,
                                                   const float* __restrict__ fss,
                                                   const unsigned* __restrict__ fmaxu,
                                                   const float* __restrict__ fc1w,
                                                   const float* __restrict__ fc1b,
                                                   const float* __restrict__ fc2w,
                                                   const float* __restrict__ fc2b,
                                                   void* __restrict__ out,
                                                   const int* __restrict__ flag) {
  int b = blockIdx.x, o = threadIdx.x;
  __shared__ float gs[128], t1[128], ys[128];
  constexpr float invN = 1.f / N;
  float m = fsum[b * 128 + o] * invN;
  float v = fmaxf(fss[b * 128 + o] * invN - m * m, 0.f);
  unsigned u = fmaxu[b * 128 + o];
  unsigned bits = (u & 0x80000000u) ? (u ^ 0x80000000u) : ~u;
  float fx = __uint_as_float(bits);
  gs[o] = lrelu((fx - m) * rsqrtf(v + EPS));
  __syncthreads();
  float a = fc1b[o];
  for (int c = 0; c < 128; ++c) a += fc1w[o * 128 + c] * gs[c];
  t1[o] = a;
  __syncthreads();
  float mm = 0.f;
  for (int c = 0; c < 128; ++c) mm += t1[c];
  mm *= (1.f / 128);
  float vv = 0.f;
  for (int c = 0; c < 128; ++c) {
    float d = t1[c] - mm;
    vv += d * d;
  }
  vv *= (1.f / 128);
  ys[o] = lrelu((a - mm) * rsqrtf(vv + EPS));
  __syncthreads();
  float r = fc2b[o];
  for (int c = 0; c < 128; ++c) r += fc2w[o * 128 + c] * ys[c];
  if (flag[0])
    ((float*)out)[b * 128 + o] = r;
  else
    ((bf16*)out)[b * 128 + o] = __float2bfloat16(r);
}

// ---------------------------------------------------------------- driver
template <int C, int O>
static void run_layer(const float* h, int hstride, float* featdst, const float* Wp,
                      float* cstats, float* distproj, int* idxb, hipStream_t stream) {
  dist_kernel<C><<<dim3(N / 128, N / 128, B), 256, 0, stream>>>(h, hstride, distproj);
  select_kernel<<<B * N / 4, 256, 0, stream>>>(distproj, idxb);
  // dist is dead after select; reuse the buffer for proj [BN][2O]
  proj_kernel<C, 2 * O><<<dim3(2 * O / 64, B * N / 64), 256, 0, stream>>>(h, hstride, Wp,
                                                                          distproj);
  edge_reduce_kernel<O><<<B * N / (256 / O), 256, 0, stream>>>(distproj, idxb, cstats,
                                                               featdst);
  finalize_kernel<<<B * N * O / 256, 256, 0, stream>>>(cstats, featdst, O);
}

extern "C" void kernel_launch(void* const* d_in, const int* in_sizes, int n_in,
                              void* d_out, int out_size, void* d_ws, size_t ws_size,
                              hipStream_t stream) {
  float* ws = (float*)d_ws;
  float* xf = ws + O_XF;
  float* feats = ws + O_FEATS;
  float* distproj = ws + O_DIST;
  int* idxb = (int*)(ws + O_IDX);
  int* flag = (int*)(ws + O_FLAG);

  prep_kernel<<<(PREP_TOTAL + 255) / 256, 256, 0, stream>>>(
      d_in[0], d_in[2], d_in[3], d_in[4], d_in[5], d_in[6], d_in[7], d_in[8], d_in[9],
      d_in[10], ws);

  run_layer<3, 32>(xf, 3, feats + 0, ws + O_WP0, ws + O_CS0, distproj, idxb, stream);
  run_layer<32, 64>(feats + 0, FD, feats + 32, ws + O_WP1, ws + O_CS1, distproj, idxb, stream);
  run_layer<64, 128>(feats + 32, FD, feats + 96, ws + O_WP2, ws + O_CS2, distproj, idxb,
                     stream);
  run_layer<128, 256>(feats + 96, FD, feats + 224, ws + O_WP3, ws + O_CS3, distproj, idxb,
                      stream);

  fstage_kernel<<<B * 128, 256, 0, stream>>>(feats, ws + O_WHT, ws + O_FSUM, ws + O_FSS,
                                             (unsigned*)(ws + O_FMAX));
  head_kernel<<<B, 128, 0, stream>>>(ws + O_FSUM, ws + O_FSS, (unsigned*)(ws + O_FMAX),
                                     ws + O_F1W, ws + O_F1B, ws + O_F2W, ws + O_F2B, d_out,
                                     flag);
}

// Round 12
// 1059.349 us; speedup vs baseline: 2.0558x; 1.0429x over previous
//
#include <hip/hip_runtime.h>
#include <hip/hip_bf16.h>
#include <cstdint>

using bf16 = __hip_bfloat16;

static constexpr int B = 2;
static constexpr int N = 2048;
static constexpr int KNN = 32;
static constexpr int FD = 480;
static constexpr float EPS = 1e-5f;
static constexpr float SLOPE = 0.2f;

// ---------------- workspace layout (floats), all compile-time ----------------
static constexpr size_t N_XF = (size_t)B * N * 3;
static constexpr size_t N_FEATS = (size_t)B * N * FD;
static constexpr size_t N_DIST = (size_t)B * N * N;   // also reused as proj [BN][2O]
static constexpr size_t N_IDX = (size_t)B * N * KNN;
static constexpr size_t O_XF = 0;
static constexpr size_t O_FEATS = O_XF + N_XF;
static constexpr size_t O_DIST = O_FEATS + N_FEATS;
static constexpr size_t O_IDX = O_DIST + N_DIST;
static constexpr size_t O_WP0 = O_IDX + N_IDX;        // [3][64]
static constexpr size_t O_WP1 = O_WP0 + 192;          // [32][128]
static constexpr size_t O_WP2 = O_WP1 + 4096;         // [64][256]
static constexpr size_t O_WP3 = O_WP2 + 16384;        // [128][512]
static constexpr size_t O_WHT = O_WP3 + 65536;
static constexpr size_t O_F1W = O_WHT + 61440;
static constexpr size_t O_F1B = O_F1W + 16384;
static constexpr size_t O_F2W = O_F1B + 128;
static constexpr size_t O_F2B = O_F2W + 16384;
static constexpr size_t O_FLAG = O_F2B + 128;
static constexpr size_t O_CS0 = O_FLAG + 16;   // zero region starts here
static constexpr size_t O_CS1 = O_CS0 + 128;
static constexpr size_t O_CS2 = O_CS1 + 256;
static constexpr size_t O_CS3 = O_CS2 + 512;
static constexpr size_t O_FSUM = O_CS3 + 1024;
static constexpr size_t O_FSS = O_FSUM + 256;
static constexpr size_t O_FMAX = O_FSS + 256;
static constexpr size_t O_END = O_FMAX + 256;
static constexpr size_t N_ZERO = O_END - O_CS0;

__device__ __forceinline__ float lrelu(float x) { return x >= 0.f ? x : SLOPE * x; }

__device__ __forceinline__ float load_in(const void* p, int i, int isf32) {
  return isf32 ? ((const float*)p)[i] : __bfloat162float(((const bf16*)p)[i]);
}

// ---------------------------------------------------------------- prep (fused)
// Edge-layer weights are stored projected: Wproj[c][o] = Wd[o][c] (o<O),
// Wproj[c][O+o] = Wc[o][c] - Wd[o][c]. Then edge e[n,k,o] =
// (h[j_k]·Wproj)[o] + (h[n]·Wproj)[O+o] — 1x1 conv distributes over concat.
static constexpr int PREP_TOTAL =
    (int)(N_XF + 96 + 2048 + 8192 + 32768 + 61440 + 16384 + 128 + 16384 + 128 + N_ZERO);

__global__ __launch_bounds__(256) void prep_kernel(
    const void* __restrict__ x, const void* __restrict__ W0, const void* __restrict__ W1,
    const void* __restrict__ W2, const void* __restrict__ W3, const void* __restrict__ Wh,
    const void* __restrict__ fc1w, const void* __restrict__ fc1b,
    const void* __restrict__ fc2w, const void* __restrict__ fc2b, float* __restrict__ ws) {
  __shared__ float red[256];
  const unsigned short* xr = (const unsigned short*)x;
  float mx = 0.f;
  for (int i = threadIdx.x; i < B * N * 3; i += 256) {
    float v = __uint_as_float(((unsigned)xr[i]) << 16);
    v = fabsf(v);
    if (!(v < 1e30f)) v = 1e30f;  // NaN/inf -> huge
    mx = fmaxf(mx, v);
  }
  red[threadIdx.x] = mx;
  __syncthreads();
  for (int s = 128; s > 0; s >>= 1) {
    if (threadIdx.x < s) red[threadIdx.x] = fmaxf(red[threadIdx.x], red[threadIdx.x + s]);
    __syncthreads();
  }
  int isf = red[0] > 1e3f ? 1 : 0;
  if (blockIdx.x == 0 && threadIdx.x == 0) ((int*)(ws + O_FLAG))[0] = isf;

  int idx = blockIdx.x * 256 + threadIdx.x;
  if (idx < (int)N_XF) { ws[O_XF + idx] = load_in(x, idx, isf); return; }
  idx -= (int)N_XF;
  if (idx < 96) {  // W0: O=32,C=3
    int o = idx / 3, c = idx - o * 3;
    float a = load_in(W0, o * 6 + c, isf);
    float bb = load_in(W0, o * 6 + 3 + c, isf);
    ws[O_WP0 + c * 64 + o] = a;
    ws[O_WP0 + c * 64 + 32 + o] = bb - a;
    return;
  }
  idx -= 96;
  if (idx < 2048) {  // W1: O=64,C=32
    int o = idx >> 5, c = idx & 31;
    float a = load_in(W1, o * 64 + c, isf);
    float bb = load_in(W1, o * 64 + 32 + c, isf);
    ws[O_WP1 + c * 128 + o] = a;
    ws[O_WP1 + c * 128 + 64 + o] = bb - a;
    return;
  }
  idx -= 2048;
  if (idx < 8192) {  // W2: O=128,C=64
    int o = idx >> 6, c = idx & 63;
    float a = load_in(W2, o * 128 + c, isf);
    float bb = load_in(W2, o * 128 + 64 + c, isf);
    ws[O_WP2 + c * 256 + o] = a;
    ws[O_WP2 + c * 256 + 128 + o] = bb - a;
    return;
  }
  idx -= 8192;
  if (idx < 32768) {  // W3: O=256,C=128
    int o = idx >> 7, c = idx & 127;
    float a = load_in(W3, o * 256 + c, isf);
    float bb = load_in(W3, o * 256 + 128 + c, isf);
    ws[O_WP3 + c * 512 + o] = a;
    ws[O_WP3 + c * 512 + 256 + o] = bb - a;
    return;
  }
  idx -= 32768;
  if (idx < 61440) {  // Wh [128][480] -> [480][128]
    int o = idx / 480, c = idx - o * 480;
    ws[O_WHT + c * 128 + o] = load_in(Wh, idx, isf);
    return;
  }
  idx -= 61440;
  if (idx < 16384) { ws[O_F1W + idx] = load_in(fc1w, idx, isf); return; }
  idx -= 16384;
  if (idx < 128) { ws[O_F1B + idx] = load_in(fc1b, idx, isf); return; }
  idx -= 128;
  if (idx < 16384) { ws[O_F2W + idx] = load_in(fc2w, idx, isf); return; }
  idx -= 16384;
  if (idx < 128) { ws[O_F2B + idx] = load_in(fc2b, idx, isf); return; }
  idx -= 128;
  if (idx < (int)N_ZERO) ws[O_CS0 + idx] = 0.f;
}

// ---------------------------------------------------------------- dist (sq fused)
template <int C>
__global__ __launch_bounds__(256) void dist_kernel(const float* __restrict__ h, int hstride,
                                                   float* __restrict__ dist) {
  constexpr int CW = 16;
  __shared__ float Ast[CW][132];
  __shared__ float Bst[CW][132];
  __shared__ float sqn[128], sqm[128];
  int b = blockIdx.z;
  int n0 = blockIdx.y * 128, m0 = blockIdx.x * 128;
  int tid = threadIdx.x;
  int tx = tid & 15, ty = tid >> 4;
  int rr = tid & 127;
  float dot[8][8] = {};
  float sqacc = 0.f;
  for (int cc = 0; cc < C; cc += CW) {
    for (int i = tid; i < 128 * CW; i += 256) {
      int c = i & 15, r = i >> 4;
      int gc = cc + c;
      float av = 0.f, bv = 0.f;
      if (gc < C) {
        av = h[(size_t)(b * N + n0 + r) * hstride + gc];
        bv = h[(size_t)(b * N + m0 + r) * hstride + gc];
      }
      Ast[c][r] = av;
      Bst[c][r] = bv;
    }
    __syncthreads();
    if (tid < 128) {
#pragma unroll
      for (int c = 0; c < CW; ++c) { float v = Ast[c][rr]; sqacc += v * v; }
    } else {
#pragma unroll
      for (int c = 0; c < CW; ++c) { float v = Bst[c][rr]; sqacc += v * v; }
    }
#pragma unroll
    for (int c = 0; c < CW; ++c) {
      float av[8], bv[8];
#pragma unroll
      for (int i = 0; i < 8; ++i) av[i] = Ast[c][ty * 8 + i];
#pragma unroll
      for (int j = 0; j < 8; ++j) bv[j] = Bst[c][tx * 8 + j];
#pragma unroll
      for (int i = 0; i < 8; ++i)
#pragma unroll
        for (int j = 0; j < 8; ++j) dot[i][j] += av[i] * bv[j];
    }
    __syncthreads();
  }
  if (tid < 128) sqn[rr] = sqacc; else sqm[rr] = sqacc;
  __syncthreads();
#pragma unroll
  for (int i = 0; i < 8; ++i) {
    int nn = n0 + ty * 8 + i;
    float sn = sqn[ty * 8 + i];
#pragma unroll
    for (int jq = 0; jq < 2; ++jq) {
      float4 w;
      w.x = sn + sqm[tx * 8 + jq * 4 + 0] - 2.f * dot[i][jq * 4 + 0];
      w.y = sn + sqm[tx * 8 + jq * 4 + 1] - 2.f * dot[i][jq * 4 + 1];
      w.z = sn + sqm[tx * 8 + jq * 4 + 2] - 2.f * dot[i][jq * 4 + 2];
      w.w = sn + sqm[tx * 8 + jq * 4 + 3] - 2.f * dot[i][jq * 4 + 3];
      *reinterpret_cast<float4*>(&dist[(size_t)(b * N + nn) * N + m0 + tx * 8 + jq * 4]) = w;
    }
  }
}

__device__ __forceinline__ unsigned long long wave_min_u64(unsigned long long v) {
#pragma unroll
  for (int m = 1; m < 64; m <<= 1) {
    unsigned lo = (unsigned)v;
    unsigned hi = (unsigned)(v >> 32);
    unsigned olo = (unsigned)__shfl_xor((int)lo, m, 64);
    unsigned ohi = (unsigned)__shfl_xor((int)hi, m, 64);
    unsigned long long ov = ((unsigned long long)ohi << 32) | olo;
    if (ov < v) v = ov;
  }
  return v;
}

// One wave per row; 32 u32 ordered-distance bits per lane, index implicit.
// (R11-proven: register-resident keys, no remat.)
__global__ __launch_bounds__(256) void select_kernel(const float* __restrict__ dist,
                                                     int* __restrict__ idxb) {
  int row = blockIdx.x * 4 + (threadIdx.x >> 6);  // b*N + n
  int lane = threadIdx.x & 63;
  const float* drow = dist + (size_t)row * N;
  unsigned dk[32];
#pragma unroll
  for (int j = 0; j < 32; ++j) {
    unsigned u = __float_as_uint(drow[j * 64 + lane]);
    dk[j] = (u & 0x80000000u) ? ~u : (u | 0x80000000u);
  }
  unsigned ld = dk[0];
  int lj = 0;
#pragma unroll
  for (int j = 1; j < 32; ++j) {
    if (dk[j] < ld) { ld = dk[j]; lj = j; }
  }
  unsigned saved = 0;
  for (int it = 0; it <= KNN; ++it) {
    unsigned long long lkey =
        ((unsigned long long)ld << 32) | (unsigned)(lj * 64 + lane);
    unsigned long long g = wave_min_u64(lkey);
    if (it > 0 && lane == it - 1) saved = (unsigned)(g & 0xFFFFFFFFull);
    if (lkey == g) {  // unique m per lane -> exactly one winner
#pragma unroll
      for (int j = 0; j < 32; ++j)
        if (j == lj) dk[j] = 0xFFFFFFFFu;
      ld = dk[0];
      lj = 0;
#pragma unroll
      for (int j = 1; j < 32; ++j) {
        if (dk[j] < ld) { ld = dk[j]; lj = j; }
      }
    }
  }
  if (lane < KNN) idxb[row * KNN + lane] = (int)saved;
}

// ---------------------------------------------------------------- proj GEMM
// proj[bn][o2] = sum_c h[bn][c] * Wp[c][o2], o2 in [0, 2O). 64x64 block tile,
// 4x4 per thread (R1-proven structure; VGPR-safe).
template <int C, int NO2>
__global__ __launch_bounds__(256) void proj_kernel(const float* __restrict__ h, int hstride,
                                                   const float* __restrict__ Wp,
                                                   float* __restrict__ proj) {
  constexpr int CW = 16;
  __shared__ float As[64][17];
  __shared__ float Bs[64][17];
  int n0 = blockIdx.y * 64;
  int m0 = blockIdx.x * 64;
  int tid = threadIdx.x;
  int tx = tid & 15, ty = tid >> 4;
  float dot[4][4] = {};
  for (int cc = 0; cc < C; cc += CW) {
    for (int i = tid; i < 64 * CW; i += 256) {
      int r = i >> 4, c = i & 15;
      int gc = cc + c;
      As[r][c] = (gc < C) ? h[(size_t)(n0 + r) * hstride + gc] : 0.f;
    }
    for (int i = tid; i < 64 * CW; i += 256) {
      int c = i >> 6, m = i & 63;
      int gc = cc + c;
      Bs[m][c] = (gc < C) ? Wp[(size_t)gc * NO2 + m0 + m] : 0.f;
    }
    __syncthreads();
#pragma unroll
    for (int c = 0; c < CW; ++c) {
      float av[4], bv[4];
#pragma unroll
      for (int i = 0; i < 4; ++i) av[i] = As[ty * 4 + i][c];
#pragma unroll
      for (int j = 0; j < 4; ++j) bv[j] = Bs[tx * 4 + j][c];
#pragma unroll
      for (int i = 0; i < 4; ++i)
#pragma unroll
        for (int j = 0; j < 4; ++j) dot[i][j] += av[i] * bv[j];
    }
    __syncthreads();
  }
#pragma unroll
  for (int i = 0; i < 4; ++i) {
    float4 w;
    w.x = dot[i][0];
    w.y = dot[i][1];
    w.z = dot[i][2];
    w.w = dot[i][3];
    *reinterpret_cast<float4*>(&proj[(size_t)(n0 + ty * 4 + i) * NO2 + m0 + tx * 4]) = w;
  }
}

// ---------------------------------------------------------------- edge reduce
// One bn per block for ALL layers (4096 blocks): KSPLIT = 256/O threads per
// (bn,o), each gathers KNN/KSPLIT k's with a fully unrolled loop (all loads
// in flight), partials combined across ks-slices in LDS. R11's version had
// 512-block grids for small O + unroll-4 -> latency-bound at 169 us.
template <int O>
__global__ __launch_bounds__(256) void edge_reduce_kernel(const float* __restrict__ proj,
                                                          const int* __restrict__ idxb,
                                                          float* __restrict__ cstats,
                                                          float* __restrict__ featdst) {
  constexpr int KSPLIT = 256 / O;
  constexpr int KS = KNN / KSPLIT;  // k per thread: 4/8/16/32
  constexpr int NO2 = 2 * O;
  __shared__ int knn[KNN];
  __shared__ float red[3][(KSPLIT > 1) ? KSPLIT : 1][O];
  int bn = blockIdx.x;
  int b = bn >> 11;
  int tid = threadIdx.x;
  if (tid < KNN) knn[tid] = idxb[bn * KNN + tid];
  __syncthreads();
  int ks = tid / O;
  int o = tid - ks * O;
  int jbase = b << 11;  // knn indices are within-batch; proj rows are global bn
  float h0 = proj[(size_t)bn * NO2 + O + o];
  float s = 0.f, ss = 0.f, m = -3.4e38f;
#pragma unroll
  for (int t = 0; t < KS; ++t) {
    int j = jbase + knn[ks * KS + t];
    float e = proj[(size_t)j * NO2 + o] + h0;
    s += e;
    ss += e * e;
    m = fmaxf(m, e);
  }
  if constexpr (KSPLIT > 1) {
    red[0][ks][o] = s;
    red[1][ks][o] = ss;
    red[2][ks][o] = m;
    __syncthreads();
    if (ks == 0) {
#pragma unroll
      for (int q = 1; q < KSPLIT; ++q) {
        s += red[0][q][o];
        ss += red[1][q][o];
        m = fmaxf(m, red[2][q][o]);
      }
    }
  }
  if (ks == 0) {
    featdst[(size_t)bn * FD + o] = m;
    atomicAdd(&cstats[(b * O + o) * 2 + 0], s);
    atomicAdd(&cstats[(b * O + o) * 2 + 1], ss);
  }
}

// in-place: featdst = lrelu((featdst - mean) * rsqrt(var + eps))
__global__ void finalize_kernel(const float* __restrict__ cstats,
                                float* __restrict__ featdst, int O) {
  int i = blockIdx.x * 256 + threadIdx.x;
  int o = i % O;
  int bn = i / O;
  int b = bn >> 11;
  float s = cstats[(b * O + o) * 2 + 0];
  float ss = cstats[(b * O + o) * 2 + 1];
  constexpr float inv = 1.f / ((float)N * KNN);
  float m = s * inv;
  float v = fmaxf(ss * inv - m * m, 0.f);
  float* p = &featdst[(size_t)bn * FD + o];
  float e = (*p - m) * rsqrtf(v + EPS);
  *p = lrelu(e);
}

// ---------------------------------------------------------------- 480 -> 128 stage
__global__ __launch_bounds__(256) void fstage_kernel(const float* __restrict__ feats,
                                                     const float* __restrict__ Wht,
                                                     float* __restrict__ fsum,
                                                     float* __restrict__ fss,
                                                     unsigned* __restrict__ fmaxu) {
  int blk = blockIdx.x;
  int b = blk >> 7;
  int n0 = (blk & 127) * 16;
  int tid = threadIdx.x;
  __shared__ float rows[16][FD];
  __shared__ float red[3][2][128];
  for (int i = tid; i < 16 * FD; i += 256) {
    int r = i / FD, c = i - r * FD;
    rows[r][c] = feats[(size_t)(b * N + n0 + r) * FD + c];
  }
  __syncthreads();
  int o = tid & 127, g = tid >> 7;
  float acc[8] = {};
  for (int c = 0; c < FD; ++c) {
    float w = Wht[c * 128 + o];
#pragma unroll
    for (int j = 0; j < 8; ++j) acc[j] += w * rows[g * 8 + j][c];
  }
  float s = 0.f, ss = 0.f, mx = -3.4e38f;
#pragma unroll
  for (int j = 0; j < 8; ++j) {
    float f = acc[j];
    s += f;
    ss += f * f;
    mx = fmaxf(mx, f);
  }
  red[0][g][o] = s;
  red[1][g][o] = ss;
  red[2][g][o] = mx;
  __syncthreads();
  if (g == 0) {
    s += red[0][1][o];
    ss += red[1][1][o];
    mx = fmaxf(mx, red[2][1][o]);
    atomicAdd(&fsum[b * 128 + o], s);
    atomicAdd(&fss[b * 128 + o], ss);
    unsigned u = __float_as_uint(mx);
    u = (u & 0x80000000u) ? ~u : (u | 0x80000000u);
    atomicMax(&fmaxu[b * 128 + o], u);
  }
}

// ---------------------------------------------------------------- head
__global__ __launch_bounds__(128) void head_kernel(const float* __restrict__ fsum,
                                                   const float* __restrict__ fss,
                                                   const unsigned* __restrict__ fmaxu,
                                                   const float* __restrict__ fc1w,
                                                   const float* __restrict__ fc1b,
                                                   const float* __restrict__ fc2w,
                                                   const float* __restrict__ fc2b,
                                                   void* __restrict__ out,
                                                   const int* __restrict__ flag) {
  int b = blockIdx.x, o = threadIdx.x;
  __shared__ float gs[128], t1[128], ys[128];
  constexpr float invN = 1.f / N;
  float m = fsum[b * 128 + o] * invN;
  float v = fmaxf(fss[b * 128 + o] * invN - m * m, 0.f);
  unsigned u = fmaxu[b * 128 + o];
  unsigned bits = (u & 0x80000000u) ? (u ^ 0x80000000u) : ~u;
  float fx = __uint_as_float(bits);
  gs[o] = lrelu((fx - m) * rsqrtf(v + EPS));
  __syncthreads();
  float a = fc1b[o];
  for (int c = 0; c < 128; ++c) a += fc1w[o * 128 + c] * gs[c];
  t1[o] = a;
  __syncthreads();
  float mm = 0.f;
  for (int c = 0; c < 128; ++c) mm += t1[c];
  mm *= (1.f / 128);
  float vv = 0.f;
  for (int c = 0; c < 128; ++c) {
    float d = t1[c] - mm;
    vv += d * d;
  }
  vv *= (1.f / 128);
  ys[o] = lrelu((a - mm) * rsqrtf(vv + EPS));
  __syncthreads();
  float r = fc2b[o];
  for (int c = 0; c < 128; ++c) r += fc2w[o * 128 + c] * ys[c];
  if (flag[0])
    ((float*)out)[b * 128 + o] = r;
  else
    ((bf16*)out)[b * 128 + o] = __float2bfloat16(r);
}

// ---------------------------------------------------------------- driver
template <int C, int O>
static void run_layer(const float* h, int hstride, float* featdst, const float* Wp,
                      float* cstats, float* distproj, int* idxb, hipStream_t stream) {
  dist_kernel<C><<<dim3(N / 128, N / 128, B), 256, 0, stream>>>(h, hstride, distproj);
  select_kernel<<<B * N / 4, 256, 0, stream>>>(distproj, idxb);
  // dist is dead after select; reuse the buffer for proj [BN][2O]
  proj_kernel<C, 2 * O><<<dim3(2 * O / 64, B * N / 64), 256, 0, stream>>>(h, hstride, Wp,
                                                                          distproj);
  edge_reduce_kernel<O><<<B * N, 256, 0, stream>>>(distproj, idxb, cstats, featdst);
  finalize_kernel<<<B * N * O / 256, 256, 0, stream>>>(cstats, featdst, O);
}

extern "C" void kernel_launch(void* const* d_in, const int* in_sizes, int n_in,
                              void* d_out, int out_size, void* d_ws, size_t ws_size,
                              hipStream_t stream) {
  float* ws = (float*)d_ws;
  float* xf = ws + O_XF;
  float* feats = ws + O_FEATS;
  float* distproj = ws + O_DIST;
  int* idxb = (int*)(ws + O_IDX);
  int* flag = (int*)(ws + O_FLAG);

  prep_kernel<<<(PREP_TOTAL + 255) / 256, 256, 0, stream>>>(
      d_in[0], d_in[2], d_in[3], d_in[4], d_in[5], d_in[6], d_in[7], d_in[8], d_in[9],
      d_in[10], ws);

  run_layer<3, 32>(xf, 3, feats + 0, ws + O_WP0, ws + O_CS0, distproj, idxb, stream);
  run_layer<32, 64>(feats + 0, FD, feats + 32, ws + O_WP1, ws + O_CS1, distproj, idxb, stream);
  run_layer<64, 128>(feats + 32, FD, feats + 96, ws + O_WP2, ws + O_CS2, distproj, idxb,
                     stream);
  run_layer<128, 256>(feats + 96, FD, feats + 224, ws + O_WP3, ws + O_CS3, distproj, idxb,
                      stream);

  fstage_kernel<<<B * 128, 256, 0, stream>>>(feats, ws + O_WHT, ws + O_FSUM, ws + O_FSS,
                                             (unsigned*)(ws + O_FMAX));
  head_kernel<<<B, 128, 0, stream>>>(ws + O_FSUM, ws + O_FSS, (unsigned*)(ws + O_FMAX),
                                     ws + O_F1W, ws + O_F1B, ws + O_F2W, ws + O_F2B, d_out,
                                     flag);
}

// Round 13
// 1045.428 us; speedup vs baseline: 2.0831x; 1.0133x over previous
//
#include <hip/hip_runtime.h>
#include <hip/hip_bf16.h>
#include <cstdint>

using bf16 = __hip_bfloat16;

static constexpr int B = 2;
static constexpr int N = 2048;
static constexpr int KNN = 32;
static constexpr int FD = 480;
static constexpr float EPS = 1e-5f;
static constexpr float SLOPE = 0.2f;

// ---------------- workspace layout (floats), all compile-time ----------------
static constexpr size_t N_XF = (size_t)B * N * 3;
static constexpr size_t N_FEATS = (size_t)B * N * FD;
static constexpr size_t N_DIST = (size_t)B * N * N;   // also reused as proj [BN][2O]
static constexpr size_t N_IDX = (size_t)B * N * KNN;
static constexpr size_t O_XF = 0;
static constexpr size_t O_FEATS = O_XF + N_XF;
static constexpr size_t O_DIST = O_FEATS + N_FEATS;
static constexpr size_t O_IDX = O_DIST + N_DIST;
static constexpr size_t O_WP0 = O_IDX + N_IDX;        // [3][64]
static constexpr size_t O_WP1 = O_WP0 + 192;          // [32][128]
static constexpr size_t O_WP2 = O_WP1 + 4096;         // [64][256]
static constexpr size_t O_WP3 = O_WP2 + 16384;        // [128][512]
static constexpr size_t O_WHT = O_WP3 + 65536;
static constexpr size_t O_F1W = O_WHT + 61440;
static constexpr size_t O_F1B = O_F1W + 16384;
static constexpr size_t O_F2W = O_F1B + 128;
static constexpr size_t O_F2B = O_F2W + 16384;
static constexpr size_t O_FLAG = O_F2B + 128;
static constexpr size_t O_CS0 = O_FLAG + 16;   // zero region starts here
static constexpr size_t O_CS1 = O_CS0 + 128;
static constexpr size_t O_CS2 = O_CS1 + 256;
static constexpr size_t O_CS3 = O_CS2 + 512;
static constexpr size_t O_FSUM = O_CS3 + 1024;
static constexpr size_t O_FSS = O_FSUM + 256;
static constexpr size_t O_FMAX = O_FSS + 256;
static constexpr size_t O_END = O_FMAX + 256;
static constexpr size_t N_ZERO = O_END - O_CS0;

__device__ __forceinline__ float lrelu(float x) { return x >= 0.f ? x : SLOPE * x; }

__device__ __forceinline__ float load_in(const void* p, int i, int isf32) {
  return isf32 ? ((const float*)p)[i] : __bfloat162float(((const bf16*)p)[i]);
}

// ---------------------------------------------------------------- prep (fused)
// Edge-layer weights are stored projected: Wproj[c][o] = Wd[o][c] (o<O),
// Wproj[c][O+o] = Wc[o][c] - Wd[o][c]. Then edge e[n,k,o] =
// (h[j_k]·Wproj)[o] + (h[n]·Wproj)[O+o] — 1x1 conv distributes over concat.
static constexpr int PREP_TOTAL =
    (int)(N_XF + 96 + 2048 + 8192 + 32768 + 61440 + 16384 + 128 + 16384 + 128 + N_ZERO);

__global__ __launch_bounds__(256) void prep_kernel(
    const void* __restrict__ x, const void* __restrict__ W0, const void* __restrict__ W1,
    const void* __restrict__ W2, const void* __restrict__ W3, const void* __restrict__ Wh,
    const void* __restrict__ fc1w, const void* __restrict__ fc1b,
    const void* __restrict__ fc2w, const void* __restrict__ fc2b, float* __restrict__ ws) {
  __shared__ float red[256];
  const unsigned short* xr = (const unsigned short*)x;
  float mx = 0.f;
  for (int i = threadIdx.x; i < B * N * 3; i += 256) {
    float v = __uint_as_float(((unsigned)xr[i]) << 16);
    v = fabsf(v);
    if (!(v < 1e30f)) v = 1e30f;  // NaN/inf -> huge
    mx = fmaxf(mx, v);
  }
  red[threadIdx.x] = mx;
  __syncthreads();
  for (int s = 128; s > 0; s >>= 1) {
    if (threadIdx.x < s) red[threadIdx.x] = fmaxf(red[threadIdx.x], red[threadIdx.x + s]);
    __syncthreads();
  }
  int isf = red[0] > 1e3f ? 1 : 0;
  if (blockIdx.x == 0 && threadIdx.x == 0) ((int*)(ws + O_FLAG))[0] = isf;

  int idx = blockIdx.x * 256 + threadIdx.x;
  if (idx < (int)N_XF) { ws[O_XF + idx] = load_in(x, idx, isf); return; }
  idx -= (int)N_XF;
  if (idx < 96) {  // W0: O=32,C=3
    int o = idx / 3, c = idx - o * 3;
    float a = load_in(W0, o * 6 + c, isf);
    float bb = load_in(W0, o * 6 + 3 + c, isf);
    ws[O_WP0 + c * 64 + o] = a;
    ws[O_WP0 + c * 64 + 32 + o] = bb - a;
    return;
  }
  idx -= 96;
  if (idx < 2048) {  // W1: O=64,C=32
    int o = idx >> 5, c = idx & 31;
    float a = load_in(W1, o * 64 + c, isf);
    float bb = load_in(W1, o * 64 + 32 + c, isf);
    ws[O_WP1 + c * 128 + o] = a;
    ws[O_WP1 + c * 128 + 64 + o] = bb - a;
    return;
  }
  idx -= 2048;
  if (idx < 8192) {  // W2: O=128,C=64
    int o = idx >> 6, c = idx & 63;
    float a = load_in(W2, o * 128 + c, isf);
    float bb = load_in(W2, o * 128 + 64 + c, isf);
    ws[O_WP2 + c * 256 + o] = a;
    ws[O_WP2 + c * 256 + 128 + o] = bb - a;
    return;
  }
  idx -= 8192;
  if (idx < 32768) {  // W3: O=256,C=128
    int o = idx >> 7, c = idx & 127;
    float a = load_in(W3, o * 256 + c, isf);
    float bb = load_in(W3, o * 256 + 128 + c, isf);
    ws[O_WP3 + c * 512 + o] = a;
    ws[O_WP3 + c * 512 + 256 + o] = bb - a;
    return;
  }
  idx -= 32768;
  if (idx < 61440) {  // Wh [128][480] -> [480][128]
    int o = idx / 480, c = idx - o * 480;
    ws[O_WHT + c * 128 + o] = load_in(Wh, idx, isf);
    return;
  }
  idx -= 61440;
  if (idx < 16384) { ws[O_F1W + idx] = load_in(fc1w, idx, isf); return; }
  idx -= 16384;
  if (idx < 128) { ws[O_F1B + idx] = load_in(fc1b, idx, isf); return; }
  idx -= 128;
  if (idx < 16384) { ws[O_F2W + idx] = load_in(fc2w, idx, isf); return; }
  idx -= 16384;
  if (idx < 128) { ws[O_F2B + idx] = load_in(fc2b, idx, isf); return; }
  idx -= 128;
  if (idx < (int)N_ZERO) ws[O_CS0 + idx] = 0.f;
}

// ---------------------------------------------------------------- dist (sq fused)
template <int C>
__global__ __launch_bounds__(256) void dist_kernel(const float* __restrict__ h, int hstride,
                                                   float* __restrict__ dist) {
  constexpr int CW = 16;
  __shared__ float Ast[CW][132];
  __shared__ float Bst[CW][132];
  __shared__ float sqn[128], sqm[128];
  int b = blockIdx.z;
  int n0 = blockIdx.y * 128, m0 = blockIdx.x * 128;
  int tid = threadIdx.x;
  int tx = tid & 15, ty = tid >> 4;
  int rr = tid & 127;
  float dot[8][8] = {};
  float sqacc = 0.f;
  for (int cc = 0; cc < C; cc += CW) {
    for (int i = tid; i < 128 * CW; i += 256) {
      int c = i & 15, r = i >> 4;
      int gc = cc + c;
      float av = 0.f, bv = 0.f;
      if (gc < C) {
        av = h[(size_t)(b * N + n0 + r) * hstride + gc];
        bv = h[(size_t)(b * N + m0 + r) * hstride + gc];
      }
      Ast[c][r] = av;
      Bst[c][r] = bv;
    }
    __syncthreads();
    if (tid < 128) {
#pragma unroll
      for (int c = 0; c < CW; ++c) { float v = Ast[c][rr]; sqacc += v * v; }
    } else {
#pragma unroll
      for (int c = 0; c < CW; ++c) { float v = Bst[c][rr]; sqacc += v * v; }
    }
#pragma unroll
    for (int c = 0; c < CW; ++c) {
      float av[8], bv[8];
#pragma unroll
      for (int i = 0; i < 8; ++i) av[i] = Ast[c][ty * 8 + i];
#pragma unroll
      for (int j = 0; j < 8; ++j) bv[j] = Bst[c][tx * 8 + j];
#pragma unroll
      for (int i = 0; i < 8; ++i)
#pragma unroll
        for (int j = 0; j < 8; ++j) dot[i][j] += av[i] * bv[j];
    }
    __syncthreads();
  }
  if (tid < 128) sqn[rr] = sqacc; else sqm[rr] = sqacc;
  __syncthreads();
#pragma unroll
  for (int i = 0; i < 8; ++i) {
    int nn = n0 + ty * 8 + i;
    float sn = sqn[ty * 8 + i];
#pragma unroll
    for (int jq = 0; jq < 2; ++jq) {
      float4 w;
      w.x = sn + sqm[tx * 8 + jq * 4 + 0] - 2.f * dot[i][jq * 4 + 0];
      w.y = sn + sqm[tx * 8 + jq * 4 + 1] - 2.f * dot[i][jq * 4 + 1];
      w.z = sn + sqm[tx * 8 + jq * 4 + 2] - 2.f * dot[i][jq * 4 + 2];
      w.w = sn + sqm[tx * 8 + jq * 4 + 3] - 2.f * dot[i][jq * 4 + 3];
      *reinterpret_cast<float4*>(&dist[(size_t)(b * N + nn) * N + m0 + tx * 8 + jq * 4]) = w;
    }
  }
}

__device__ __forceinline__ unsigned long long wave_min_u64(unsigned long long v) {
#pragma unroll
  for (int m = 1; m < 64; m <<= 1) {
    unsigned lo = (unsigned)v;
    unsigned hi = (unsigned)(v >> 32);
    unsigned olo = (unsigned)__shfl_xor((int)lo, m, 64);
    unsigned ohi = (unsigned)__shfl_xor((int)hi, m, 64);
    unsigned long long ov = ((unsigned long long)ohi << 32) | olo;
    if (ov < v) v = ov;
  }
  return v;
}

// One wave per row; 32 u32 ordered-distance bits per lane, index implicit.
// (R11-proven: register-resident keys, no remat.)
__global__ __launch_bounds__(256) void select_kernel(const float* __restrict__ dist,
                                                     int* __restrict__ idxb) {
  int row = blockIdx.x * 4 + (threadIdx.x >> 6);  // b*N + n
  int lane = threadIdx.x & 63;
  const float* drow = dist + (size_t)row * N;
  unsigned dk[32];
#pragma unroll
  for (int j = 0; j < 32; ++j) {
    unsigned u = __float_as_uint(drow[j * 64 + lane]);
    dk[j] = (u & 0x80000000u) ? ~u : (u | 0x80000000u);
  }
  unsigned ld = dk[0];
  int lj = 0;
#pragma unroll
  for (int j = 1; j < 32; ++j) {
    if (dk[j] < ld) { ld = dk[j]; lj = j; }
  }
  unsigned saved = 0;
  for (int it = 0; it <= KNN; ++it) {
    unsigned long long lkey =
        ((unsigned long long)ld << 32) | (unsigned)(lj * 64 + lane);
    unsigned long long g = wave_min_u64(lkey);
    if (it > 0 && lane == it - 1) saved = (unsigned)(g & 0xFFFFFFFFull);
    if (lkey == g) {  // unique m per lane -> exactly one winner
#pragma unroll
      for (int j = 0; j < 32; ++j)
        if (j == lj) dk[j] = 0xFFFFFFFFu;
      ld = dk[0];
      lj = 0;
#pragma unroll
      for (int j = 1; j < 32; ++j) {
        if (dk[j] < ld) { ld = dk[j]; lj = j; }
      }
    }
  }
  if (lane < KNN) idxb[row * KNN + lane] = (int)saved;
}

// ---------------------------------------------------------------- proj GEMM
// proj[bn][o2] = sum_c h[bn][c] * Wp[c][o2], o2 in [0, 2O). 64x64 block tile,
// 4x4 per thread (R1-proven structure; VGPR-safe).
template <int C, int NO2>
__global__ __launch_bounds__(256) void proj_kernel(const float* __restrict__ h, int hstride,
                                                   const float* __restrict__ Wp,
                                                   float* __restrict__ proj) {
  constexpr int CW = 16;
  __shared__ float As[64][17];
  __shared__ float Bs[64][17];
  int n0 = blockIdx.y * 64;
  int m0 = blockIdx.x * 64;
  int tid = threadIdx.x;
  int tx = tid & 15, ty = tid >> 4;
  float dot[4][4] = {};
  for (int cc = 0; cc < C; cc += CW) {
    for (int i = tid; i < 64 * CW; i += 256) {
      int r = i >> 4, c = i & 15;
      int gc = cc + c;
      As[r][c] = (gc < C) ? h[(size_t)(n0 + r) * hstride + gc] : 0.f;
    }
    for (int i = tid; i < 64 * CW; i += 256) {
      int c = i >> 6, m = i & 63;
      int gc = cc + c;
      Bs[m][c] = (gc < C) ? Wp[(size_t)gc * NO2 + m0 + m] : 0.f;
    }
    __syncthreads();
#pragma unroll
    for (int c = 0; c < CW; ++c) {
      float av[4], bv[4];
#pragma unroll
      for (int i = 0; i < 4; ++i) av[i] = As[ty * 4 + i][c];
#pragma unroll
      for (int j = 0; j < 4; ++j) bv[j] = Bs[tx * 4 + j][c];
#pragma unroll
      for (int i = 0; i < 4; ++i)
#pragma unroll
        for (int j = 0; j < 4; ++j) dot[i][j] += av[i] * bv[j];
    }
    __syncthreads();
  }
#pragma unroll
  for (int i = 0; i < 4; ++i) {
    float4 w;
    w.x = dot[i][0];
    w.y = dot[i][1];
    w.z = dot[i][2];
    w.w = dot[i][3];
    *reinterpret_cast<float4*>(&proj[(size_t)(n0 + ty * 4 + i) * NO2 + m0 + tx * 4]) = w;
  }
}

// ---------------------------------------------------------------- edge reduce
// CH=4 bn per block; thread = (ks, q): float4 gathers over o-quads, KS loads
// prefetched into v[KS] (constant-indexed, full unroll -> MLP=KS). s/ss
// accumulate in registers across the chunk -> atomics /CH (R12: 2M lane-
// atomics on 4KB cstats + MLP~4 from VGPR=20 were the latency floor).
template <int O>
__global__ __launch_bounds__(256) void edge_reduce_kernel(const float* __restrict__ proj,
                                                          const int* __restrict__ idxb,
                                                          float* __restrict__ cstats,
                                                          float* __restrict__ featdst) {
  constexpr int Q = O / 4;          // float4 quads per half-row
  constexpr int KSPLIT = 256 / Q;   // k-slices
  constexpr int KS = KNN / KSPLIT;  // k per thread: 1/2/4/8
  constexpr int CH = 4;             // bn per block
  constexpr int NO2 = 2 * O;
  __shared__ int knn[CH * KNN];
  __shared__ float4 redm[KSPLIT][Q];
  __shared__ float4 red2[2][KSPLIT][Q];
  int bn0 = blockIdx.x * CH;
  int b = bn0 >> 11;  // CH divides N -> chunk stays within one batch
  int tid = threadIdx.x;
  int ks = tid / Q;
  int q = tid - ks * Q;
  if (tid < CH * KNN) knn[tid] = idxb[bn0 * KNN + tid];
  __syncthreads();
  int jbase = b << 11;  // knn indices are within-batch; proj rows are global bn
  float4 s = {0.f, 0.f, 0.f, 0.f}, ss = {0.f, 0.f, 0.f, 0.f};
  for (int cc = 0; cc < CH; ++cc) {
    int bn = bn0 + cc;
    const float4 h0 =
        *reinterpret_cast<const float4*>(&proj[(size_t)bn * NO2 + O + q * 4]);
    float4 v[KS];
#pragma unroll
    for (int t = 0; t < KS; ++t) {
      int j = jbase + knn[cc * KNN + ks * KS + t];
      v[t] = *reinterpret_cast<const float4*>(&proj[(size_t)j * NO2 + q * 4]);
    }
    float4 mx = {-3.4e38f, -3.4e38f, -3.4e38f, -3.4e38f};
#pragma unroll
    for (int t = 0; t < KS; ++t) {
      float ex = v[t].x + h0.x;
      float ey = v[t].y + h0.y;
      float ez = v[t].z + h0.z;
      float ew = v[t].w + h0.w;
      s.x += ex; ss.x += ex * ex; mx.x = fmaxf(mx.x, ex);
      s.y += ey; ss.y += ey * ey; mx.y = fmaxf(mx.y, ey);
      s.z += ez; ss.z += ez * ez; mx.z = fmaxf(mx.z, ez);
      s.w += ew; ss.w += ew * ew; mx.w = fmaxf(mx.w, ew);
    }
    redm[ks][q] = mx;
    __syncthreads();
    if (ks == 0) {
      float4 m = redm[0][q];
#pragma unroll
      for (int r = 1; r < KSPLIT; ++r) {
        float4 t = redm[r][q];
        m.x = fmaxf(m.x, t.x);
        m.y = fmaxf(m.y, t.y);
        m.z = fmaxf(m.z, t.z);
        m.w = fmaxf(m.w, t.w);
      }
      *reinterpret_cast<float4*>(&featdst[(size_t)bn * FD + q * 4]) = m;
    }
    __syncthreads();
  }
  red2[0][ks][q] = s;
  red2[1][ks][q] = ss;
  __syncthreads();
  if (ks == 0) {
#pragma unroll
    for (int r = 1; r < KSPLIT; ++r) {
      float4 t0 = red2[0][r][q];
      float4 t1 = red2[1][r][q];
      s.x += t0.x; s.y += t0.y; s.z += t0.z; s.w += t0.w;
      ss.x += t1.x; ss.y += t1.y; ss.z += t1.z; ss.w += t1.w;
    }
    int o = q * 4;
    atomicAdd(&cstats[(b * O + o + 0) * 2 + 0], s.x);
    atomicAdd(&cstats[(b * O + o + 0) * 2 + 1], ss.x);
    atomicAdd(&cstats[(b * O + o + 1) * 2 + 0], s.y);
    atomicAdd(&cstats[(b * O + o + 1) * 2 + 1], ss.y);
    atomicAdd(&cstats[(b * O + o + 2) * 2 + 0], s.z);
    atomicAdd(&cstats[(b * O + o + 2) * 2 + 1], ss.z);
    atomicAdd(&cstats[(b * O + o + 3) * 2 + 0], s.w);
    atomicAdd(&cstats[(b * O + o + 3) * 2 + 1], ss.w);
  }
}

// in-place: featdst = lrelu((featdst - mean) * rsqrt(var + eps))
__global__ void finalize_kernel(const float* __restrict__ cstats,
                                float* __restrict__ featdst, int O) {
  int i = blockIdx.x * 256 + threadIdx.x;
  int o = i % O;
  int bn = i / O;
  int b = bn >> 11;
  float s = cstats[(b * O + o) * 2 + 0];
  float ss = cstats[(b * O + o) * 2 + 1];
  constexpr float inv = 1.f / ((float)N * KNN);
  float m = s * inv;
  float v = fmaxf(ss * inv - m * m, 0.f);
  float* p = &featdst[(size_t)bn * FD + o];
  float e = (*p - m) * rsqrtf(v + EPS);
  *p = lrelu(e);
}

// ---------------------------------------------------------------- 480 -> 128 stage
__global__ __launch_bounds__(256) void fstage_kernel(const float* __restrict__ feats,
                                                     const float* __restrict__ Wht,
                                                     float* __restrict__ fsum,
                                                     float* __restrict__ fss,
                                                     unsigned* __restrict__ fmaxu) {
  int blk = blockIdx.x;
  int b = blk >> 7;
  int n0 = (blk & 127) * 16;
  int tid = threadIdx.x;
  __shared__ float rows[16][FD];
  __shared__ float red[3][2][128];
  for (int i = tid; i < 16 * FD; i += 256) {
    int r = i / FD, c = i - r * FD;
    rows[r][c] = feats[(size_t)(b * N + n0 + r) * FD + c];
  }
  __syncthreads();
  int o = tid & 127, g = tid >> 7;
  float acc[8] = {};
  for (int c = 0; c < FD; ++c) {
    float w = Wht[c * 128 + o];
#pragma unroll
    for (int j = 0; j < 8; ++j) acc[j] += w * rows[g * 8 + j][c];
  }
  float s = 0.f, ss = 0.f, mx = -3.4e38f;
#pragma unroll
  for (int j = 0; j < 8; ++j) {
    float f = acc[j];
    s += f;
    ss += f * f;
    mx = fmaxf(mx, f);
  }
  red[0][g][o] = s;
  red[1][g][o] = ss;
  red[2][g][o] = mx;
  __syncthreads();
  if (g == 0) {
    s += red[0][1][o];
    ss += red[1][1][o];
    mx = fmaxf(mx, red[2][1][o]);
    atomicAdd(&fsum[b * 128 + o], s);
    atomicAdd(&fss[b * 128 + o], ss);
    unsigned u = __float_as_uint(mx);
    u = (u & 0x80000000u) ? ~u : (u | 0x80000000u);
    atomicMax(&fmaxu[b * 128 + o], u);
  }
}

// ---------------------------------------------------------------- head
__global__ __launch_bounds__(128) void head_kernel(const float* __restrict__ fsum,
                                                   const float* __restrict__ fss,
                                                   const unsigned* __restrict__ fmaxu,
                                                   const float* __restrict__ fc1w,
                                                   const float* __restrict__ fc1b,
                                                   const float* __restrict__ fc2w,
                                                   const float* __restrict__ fc2b,
                                                   void* __restrict__ out,
                                                   const int* __restrict__ flag) {
  int b = blockIdx.x, o = threadIdx.x;
  __shared__ float gs[128], t1[128], ys[128];
  constexpr float invN = 1.f / N;
  float m = fsum[b * 128 + o] * invN;
  float v = fmaxf(fss[b * 128 + o] * invN - m * m, 0.f);
  unsigned u = fmaxu[b * 128 + o];
  unsigned bits = (u & 0x80000000u) ? (u ^ 0x80000000u) : ~u;
  float fx = __uint_as_float(bits);
  gs[o] = lrelu((fx - m) * rsqrtf(v + EPS));
  __syncthreads();
  float a = fc1b[o];
  for (int c = 0; c < 128; ++c) a += fc1w[o * 128 + c] * gs[c];
  t1[o] = a;
  __syncthreads();
  float mm = 0.f;
  for (int c = 0; c < 128; ++c) mm += t1[c];
  mm *= (1.f / 128);
  float vv = 0.f;
  for (int c = 0; c < 128; ++c) {
    float d = t1[c] - mm;
    vv += d * d;
  }
  vv *= (1.f / 128);
  ys[o] = lrelu((a - mm) * rsqrtf(vv + EPS));
  __syncthreads();
  float r = fc2b[o];
  for (int c = 0; c < 128; ++c) r += fc2w[o * 128 + c] * ys[c];
  if (flag[0])
    ((float*)out)[b * 128 + o] = r;
  else
    ((bf16*)out)[b * 128 + o] = __float2bfloat16(r);
}

// ---------------------------------------------------------------- driver
template <int C, int O>
static void run_layer(const float* h, int hstride, float* featdst, const float* Wp,
                      float* cstats, float* distproj, int* idxb, hipStream_t stream) {
  dist_kernel<C><<<dim3(N / 128, N / 128, B), 256, 0, stream>>>(h, hstride, distproj);
  select_kernel<<<B * N / 4, 256, 0, stream>>>(distproj, idxb);
  // dist is dead after select; reuse the buffer for proj [BN][2O]
  proj_kernel<C, 2 * O><<<dim3(2 * O / 64, B * N / 64), 256, 0, stream>>>(h, hstride, Wp,
                                                                          distproj);
  edge_reduce_kernel<O><<<B * N / 4, 256, 0, stream>>>(distproj, idxb, cstats, featdst);
  finalize_kernel<<<B * N * O / 256, 256, 0, stream>>>(cstats, featdst, O);
}

extern "C" void kernel_launch(void* const* d_in, const int* in_sizes, int n_in,
                              void* d_out, int out_size, void* d_ws, size_t ws_size,
                              hipStream_t stream) {
  float* ws = (float*)d_ws;
  float* xf = ws + O_XF;
  float* feats = ws + O_FEATS;
  float* distproj = ws + O_DIST;
  int* idxb = (int*)(ws + O_IDX);
  int* flag = (int*)(ws + O_FLAG);

  prep_kernel<<<(PREP_TOTAL + 255) / 256, 256, 0, stream>>>(
      d_in[0], d_in[2], d_in[3], d_in[4], d_in[5], d_in[6], d_in[7], d_in[8], d_in[9],
      d_in[10], ws);

  run_layer<3, 32>(xf, 3, feats + 0, ws + O_WP0, ws + O_CS0, distproj, idxb, stream);
  run_layer<32, 64>(feats + 0, FD, feats + 32, ws + O_WP1, ws + O_CS1, distproj, idxb, stream);
  run_layer<64, 128>(feats + 32, FD, feats + 96, ws + O_WP2, ws + O_CS2, distproj, idxb,
                     stream);
  run_layer<128, 256>(feats + 96, FD, feats + 224, ws + O_WP3, ws + O_CS3, distproj, idxb,
                      stream);

  fstage_kernel<<<B * 128, 256, 0, stream>>>(feats, ws + O_WHT, ws + O_FSUM, ws + O_FSS,
                                             (unsigned*)(ws + O_FMAX));
  head_kernel<<<B, 128, 0, stream>>>(ws + O_FSUM, ws + O_FSS, (unsigned*)(ws + O_FMAX),
                                     ws + O_F1W, ws + O_F1B, ws + O_F2W, ws + O_F2B, d_out,
                                     flag);
}

// Round 15
// 994.630 us; speedup vs baseline: 2.1895x; 1.0511x over previous
//
#include <hip/hip_runtime.h>
#include <hip/hip_bf16.h>
#include <cstdint>

using bf16 = __hip_bfloat16;

static constexpr int B = 2;
static constexpr int N = 2048;
static constexpr int KNN = 32;
static constexpr int FD = 480;
static constexpr float EPS = 1e-5f;
static constexpr float SLOPE = 0.2f;

// ---------------- workspace layout (floats), all compile-time ----------------
static constexpr size_t N_XF = (size_t)B * N * 3;
static constexpr size_t N_FEATS = (size_t)B * N * FD;
static constexpr size_t N_DIST = (size_t)B * N * N;
static constexpr size_t N_IDX = (size_t)B * N * KNN;
static constexpr size_t N_PROJ = (size_t)B * N * 512;  // proj [BN][2O], O<=256
static constexpr size_t O_XF = 0;
static constexpr size_t O_FEATS = O_XF + N_XF;
static constexpr size_t O_DIST = O_FEATS + N_FEATS;
static constexpr size_t O_IDX = O_DIST + N_DIST;
static constexpr size_t O_PROJ = O_IDX + N_IDX;
static constexpr size_t O_WP0 = O_PROJ + N_PROJ;      // [3][64]
static constexpr size_t O_WP1 = O_WP0 + 192;          // [32][128]
static constexpr size_t O_WP2 = O_WP1 + 4096;         // [64][256]
static constexpr size_t O_WP3 = O_WP2 + 16384;        // [128][512]
static constexpr size_t O_WHT = O_WP3 + 65536;
static constexpr size_t O_F1W = O_WHT + 61440;
static constexpr size_t O_F1B = O_F1W + 16384;
static constexpr size_t O_F2W = O_F1B + 128;
static constexpr size_t O_F2B = O_F2W + 16384;
static constexpr size_t O_FLAG = O_F2B + 128;
static constexpr size_t O_CS0 = O_FLAG + 16;   // zero region starts here
static constexpr size_t O_CS1 = O_CS0 + 128;
static constexpr size_t O_CS2 = O_CS1 + 256;
static constexpr size_t O_CS3 = O_CS2 + 512;
static constexpr size_t O_FSUM = O_CS3 + 1024;
static constexpr size_t O_FSS = O_FSUM + 256;
static constexpr size_t O_FMAX = O_FSS + 256;
static constexpr size_t O_END = O_FMAX + 256;
static constexpr size_t N_ZERO = O_END - O_CS0;

__device__ __forceinline__ float lrelu(float x) { return x >= 0.f ? x : SLOPE * x; }

__device__ __forceinline__ float load_in(const void* p, int i, int isf32) {
  return isf32 ? ((const float*)p)[i] : __bfloat162float(((const bf16*)p)[i]);
}

// ---------------------------------------------------------------- prep (fused)
static constexpr int PREP_TOTAL =
    (int)(N_XF + 96 + 2048 + 8192 + 32768 + 61440 + 16384 + 128 + 16384 + 128 + N_ZERO);

__global__ __launch_bounds__(256) void prep_kernel(
    const void* __restrict__ x, const void* __restrict__ W0, const void* __restrict__ W1,
    const void* __restrict__ W2, const void* __restrict__ W3, const void* __restrict__ Wh,
    const void* __restrict__ fc1w, const void* __restrict__ fc1b,
    const void* __restrict__ fc2w, const void* __restrict__ fc2b, float* __restrict__ ws) {
  __shared__ float red[256];
  const unsigned short* xr = (const unsigned short*)x;
  float mx = 0.f;
  for (int i = threadIdx.x; i < B * N * 3; i += 256) {
    float v = __uint_as_float(((unsigned)xr[i]) << 16);
    v = fabsf(v);
    if (!(v < 1e30f)) v = 1e30f;  // NaN/inf -> huge
    mx = fmaxf(mx, v);
  }
  red[threadIdx.x] = mx;
  __syncthreads();
  for (int s = 128; s > 0; s >>= 1) {
    if (threadIdx.x < s) red[threadIdx.x] = fmaxf(red[threadIdx.x], red[threadIdx.x + s]);
    __syncthreads();
  }
  int isf = red[0] > 1e3f ? 1 : 0;
  if (blockIdx.x == 0 && threadIdx.x == 0) ((int*)(ws + O_FLAG))[0] = isf;

  int idx = blockIdx.x * 256 + threadIdx.x;
  if (idx < (int)N_XF) { ws[O_XF + idx] = load_in(x, idx, isf); return; }
  idx -= (int)N_XF;
  if (idx < 96) {  // W0: O=32,C=3
    int o = idx / 3, c = idx - o * 3;
    float a = load_in(W0, o * 6 + c, isf);
    float bb = load_in(W0, o * 6 + 3 + c, isf);
    ws[O_WP0 + c * 64 + o] = a;
    ws[O_WP0 + c * 64 + 32 + o] = bb - a;
    return;
  }
  idx -= 96;
  if (idx < 2048) {  // W1: O=64,C=32
    int o = idx >> 5, c = idx & 31;
    float a = load_in(W1, o * 64 + c, isf);
    float bb = load_in(W1, o * 64 + 32 + c, isf);
    ws[O_WP1 + c * 128 + o] = a;
    ws[O_WP1 + c * 128 + 64 + o] = bb - a;
    return;
  }
  idx -= 2048;
  if (idx < 8192) {  // W2: O=128,C=64
    int o = idx >> 6, c = idx & 63;
    float a = load_in(W2, o * 128 + c, isf);
    float bb = load_in(W2, o * 128 + 64 + c, isf);
    ws[O_WP2 + c * 256 + o] = a;
    ws[O_WP2 + c * 256 + 128 + o] = bb - a;
    return;
  }
  idx -= 8192;
  if (idx < 32768) {  // W3: O=256,C=128
    int o = idx >> 7, c = idx & 127;
    float a = load_in(W3, o * 256 + c, isf);
    float bb = load_in(W3, o * 256 + 128 + c, isf);
    ws[O_WP3 + c * 512 + o] = a;
    ws[O_WP3 + c * 512 + 256 + o] = bb - a;
    return;
  }
  idx -= 32768;
  if (idx < 61440) {  // Wh [128][480] -> [480][128]
    int o = idx / 480, c = idx - o * 480;
    ws[O_WHT + c * 128 + o] = load_in(Wh, idx, isf);
    return;
  }
  idx -= 61440;
  if (idx < 16384) { ws[O_F1W + idx] = load_in(fc1w, idx, isf); return; }
  idx -= 16384;
  if (idx < 128) { ws[O_F1B + idx] = load_in(fc1b, idx, isf); return; }
  idx -= 128;
  if (idx < 16384) { ws[O_F2W + idx] = load_in(fc2w, idx, isf); return; }
  idx -= 16384;
  if (idx < 128) { ws[O_F2B + idx] = load_in(fc2b, idx, isf); return; }
  idx -= 128;
  if (idx < (int)N_ZERO) ws[O_CS0 + idx] = 0.f;
}

// ---------------------------------------------------------------- dist (sq fused)
template <int C>
__global__ __launch_bounds__(256) void dist_kernel(const float* __restrict__ h, int hstride,
                                                   float* __restrict__ dist) {
  constexpr int CW = 16;
  __shared__ float Ast[CW][132];
  __shared__ float Bst[CW][132];
  __shared__ float sqn[128], sqm[128];
  int b = blockIdx.z;
  int n0 = blockIdx.y * 128, m0 = blockIdx.x * 128;
  int tid = threadIdx.x;
  int tx = tid & 15, ty = tid >> 4;
  int rr = tid & 127;
  float dot[8][8] = {};
  float sqacc = 0.f;
  for (int cc = 0; cc < C; cc += CW) {
    for (int i = tid; i < 128 * CW; i += 256) {
      int c = i & 15, r = i >> 4;
      int gc = cc + c;
      float av = 0.f, bv = 0.f;
      if (gc < C) {
        av = h[(size_t)(b * N + n0 + r) * hstride + gc];
        bv = h[(size_t)(b * N + m0 + r) * hstride + gc];
      }
      Ast[c][r] = av;
      Bst[c][r] = bv;
    }
    __syncthreads();
    if (tid < 128) {
#pragma unroll
      for (int c = 0; c < CW; ++c) { float v = Ast[c][rr]; sqacc += v * v; }
    } else {
#pragma unroll
      for (int c = 0; c < CW; ++c) { float v = Bst[c][rr]; sqacc += v * v; }
    }
#pragma unroll
    for (int c = 0; c < CW; ++c) {
      float av[8], bv[8];
#pragma unroll
      for (int i = 0; i < 8; ++i) av[i] = Ast[c][ty * 8 + i];
#pragma unroll
      for (int j = 0; j < 8; ++j) bv[j] = Bst[c][tx * 8 + j];
#pragma unroll
      for (int i = 0; i < 8; ++i)
#pragma unroll
        for (int j = 0; j < 8; ++j) dot[i][j] += av[i] * bv[j];
    }
    __syncthreads();
  }
  if (tid < 128) sqn[rr] = sqacc; else sqm[rr] = sqacc;
  __syncthreads();
#pragma unroll
  for (int i = 0; i < 8; ++i) {
    int nn = n0 + ty * 8 + i;
    float sn = sqn[ty * 8 + i];
#pragma unroll
    for (int jq = 0; jq < 2; ++jq) {
      float4 w;
      w.x = sn + sqm[tx * 8 + jq * 4 + 0] - 2.f * dot[i][jq * 4 + 0];
      w.y = sn + sqm[tx * 8 + jq * 4 + 1] - 2.f * dot[i][jq * 4 + 1];
      w.z = sn + sqm[tx * 8 + jq * 4 + 2] - 2.f * dot[i][jq * 4 + 2];
      w.w = sn + sqm[tx * 8 + jq * 4 + 3] - 2.f * dot[i][jq * 4 + 3];
      *reinterpret_cast<float4*>(&dist[(size_t)(b * N + nn) * N + m0 + tx * 8 + jq * 4]) = w;
    }
  }
}

__device__ __forceinline__ unsigned long long wave_min_u64(unsigned long long v) {
#pragma unroll
  for (int m = 1; m < 64; m <<= 1) {
    unsigned lo = (unsigned)v;
    unsigned hi = (unsigned)(v >> 32);
    unsigned olo = (unsigned)__shfl_xor((int)lo, m, 64);
    unsigned ohi = (unsigned)__shfl_xor((int)hi, m, 64);
    unsigned long long ov = ((unsigned long long)ohi << 32) | olo;
    if (ov < v) v = ov;
  }
  return v;
}

// ---------------------------------------------------------------- fused select || proj
// Blocks [0, NSEL): R11-proven register top-33 select (reads dist).
// Blocks [NSEL, NSEL+NPROJ): R9-proven 64x64 proj GEMM (reads h, writes projb).
// Independent work -> one dispatch, concurrent execution; proj's memory work
// overlaps select's latency-bound shuffle loops.
template <int C, int NO2>
__global__ __launch_bounds__(256) void selproj_kernel(const float* __restrict__ dist,
                                                      int* __restrict__ idxb,
                                                      const float* __restrict__ h,
                                                      int hstride,
                                                      const float* __restrict__ Wp,
                                                      float* __restrict__ projb) {
  constexpr int NSEL = B * N / 4;
  constexpr int MT = NO2 / 64;
  constexpr int CW = 16;
  __shared__ float As[64][17];
  __shared__ float Bs[64][17];
  if (blockIdx.x < NSEL) {
    int row = blockIdx.x * 4 + (threadIdx.x >> 6);  // b*N + n
    int lane = threadIdx.x & 63;
    const float* drow = dist + (size_t)row * N;
    unsigned dk[32];
#pragma unroll
    for (int j = 0; j < 32; ++j) {
      unsigned u = __float_as_uint(drow[j * 64 + lane]);
      dk[j] = (u & 0x80000000u) ? ~u : (u | 0x80000000u);
    }
    unsigned ld = dk[0];
    int lj = 0;
#pragma unroll
    for (int j = 1; j < 32; ++j) {
      if (dk[j] < ld) { ld = dk[j]; lj = j; }
    }
    unsigned saved = 0;
    for (int it = 0; it <= KNN; ++it) {
      unsigned long long lkey =
          ((unsigned long long)ld << 32) | (unsigned)(lj * 64 + lane);
      unsigned long long g = wave_min_u64(lkey);
      if (it > 0 && lane == it - 1) saved = (unsigned)(g & 0xFFFFFFFFull);
      if (lkey == g) {  // unique m per lane -> exactly one winner
#pragma unroll
        for (int j = 0; j < 32; ++j)
          if (j == lj) dk[j] = 0xFFFFFFFFu;
        ld = dk[0];
        lj = 0;
#pragma unroll
        for (int j = 1; j < 32; ++j) {
          if (dk[j] < ld) { ld = dk[j]; lj = j; }
        }
      }
    }
    if (lane < KNN) idxb[row * KNN + lane] = (int)saved;
  } else {
    int tile = blockIdx.x - NSEL;
    int m0 = (tile % MT) * 64;
    int n0 = (tile / MT) * 64;
    int tid = threadIdx.x;
    int tx = tid & 15, ty = tid >> 4;
    float dot[4][4] = {};
    for (int cc = 0; cc < C; cc += CW) {
      for (int i = tid; i < 64 * CW; i += 256) {
        int r = i >> 4, c = i & 15;
        int gc = cc + c;
        As[r][c] = (gc < C) ? h[(size_t)(n0 + r) * hstride + gc] : 0.f;
      }
      for (int i = tid; i < 64 * CW; i += 256) {
        int c = i >> 6, m = i & 63;
        int gc = cc + c;
        Bs[m][c] = (gc < C) ? Wp[(size_t)gc * NO2 + m0 + m] : 0.f;
      }
      __syncthreads();
#pragma unroll
      for (int c = 0; c < CW; ++c) {
        float av[4], bv[4];
#pragma unroll
        for (int i = 0; i < 4; ++i) av[i] = As[ty * 4 + i][c];
#pragma unroll
        for (int j = 0; j < 4; ++j) bv[j] = Bs[tx * 4 + j][c];
#pragma unroll
        for (int i = 0; i < 4; ++i)
#pragma unroll
          for (int j = 0; j < 4; ++j) dot[i][j] += av[i] * bv[j];
      }
      __syncthreads();
    }
#pragma unroll
    for (int i = 0; i < 4; ++i) {
      float4 w;
      w.x = dot[i][0];
      w.y = dot[i][1];
      w.z = dot[i][2];
      w.w = dot[i][3];
      *reinterpret_cast<float4*>(&projb[(size_t)(n0 + ty * 4 + i) * NO2 + m0 + tx * 4]) = w;
    }
  }
}

// ---------------------------------------------------------------- edge reduce
// (R13-proven) CH=4 bn per block; thread=(ks,q): float4 gathers over o-quads,
// KS loads prefetched into v[KS]; register accumulation across chunk.
template <int O>
__global__ __launch_bounds__(256) void edge_reduce_kernel(const float* __restrict__ proj,
                                                          const int* __restrict__ idxb,
                                                          float* __restrict__ cstats,
                                                          float* __restrict__ featdst) {
  constexpr int Q = O / 4;          // float4 quads per half-row
  constexpr int KSPLIT = 256 / Q;   // k-slices
  constexpr int KS = KNN / KSPLIT;  // k per thread: 1/2/4/8
  constexpr int CH = 4;             // bn per block
  constexpr int NO2 = 2 * O;
  __shared__ int knn[CH * KNN];
  __shared__ float4 redm[KSPLIT][Q];
  __shared__ float4 red2[2][KSPLIT][Q];
  int bn0 = blockIdx.x * CH;
  int b = bn0 >> 11;  // CH divides N -> chunk stays within one batch
  int tid = threadIdx.x;
  int ks = tid / Q;
  int q = tid - ks * Q;
  if (tid < CH * KNN) knn[tid] = idxb[bn0 * KNN + tid];
  __syncthreads();
  int jbase = b << 11;  // knn indices are within-batch; proj rows are global bn
  float4 s = {0.f, 0.f, 0.f, 0.f}, ss = {0.f, 0.f, 0.f, 0.f};
  for (int cc = 0; cc < CH; ++cc) {
    int bn = bn0 + cc;
    const float4 h0 =
        *reinterpret_cast<const float4*>(&proj[(size_t)bn * NO2 + O + q * 4]);
    float4 v[KS];
#pragma unroll
    for (int t = 0; t < KS; ++t) {
      int j = jbase + knn[cc * KNN + ks * KS + t];
      v[t] = *reinterpret_cast<const float4*>(&proj[(size_t)j * NO2 + q * 4]);
    }
    float4 mx = {-3.4e38f, -3.4e38f, -3.4e38f, -3.4e38f};
#pragma unroll
    for (int t = 0; t < KS; ++t) {
      float ex = v[t].x + h0.x;
      float ey = v[t].y + h0.y;
      float ez = v[t].z + h0.z;
      float ew = v[t].w + h0.w;
      s.x += ex; ss.x += ex * ex; mx.x = fmaxf(mx.x, ex);
      s.y += ey; ss.y += ey * ey; mx.y = fmaxf(mx.y, ey);
      s.z += ez; ss.z += ez * ez; mx.z = fmaxf(mx.z, ez);
      s.w += ew; ss.w += ew * ew; mx.w = fmaxf(mx.w, ew);
    }
    redm[ks][q] = mx;
    __syncthreads();
    if (ks == 0) {
      float4 m = redm[0][q];
#pragma unroll
      for (int r = 1; r < KSPLIT; ++r) {
        float4 t = redm[r][q];
        m.x = fmaxf(m.x, t.x);
        m.y = fmaxf(m.y, t.y);
        m.z = fmaxf(m.z, t.z);
        m.w = fmaxf(m.w, t.w);
      }
      *reinterpret_cast<float4*>(&featdst[(size_t)bn * FD + q * 4]) = m;
    }
    __syncthreads();
  }
  red2[0][ks][q] = s;
  red2[1][ks][q] = ss;
  __syncthreads();
  if (ks == 0) {
#pragma unroll
    for (int r = 1; r < KSPLIT; ++r) {
      float4 t0 = red2[0][r][q];
      float4 t1 = red2[1][r][q];
      s.x += t0.x; s.y += t0.y; s.z += t0.z; s.w += t0.w;
      ss.x += t1.x; ss.y += t1.y; ss.z += t1.z; ss.w += t1.w;
    }
    int o = q * 4;
    atomicAdd(&cstats[(b * O + o + 0) * 2 + 0], s.x);
    atomicAdd(&cstats[(b * O + o + 0) * 2 + 1], ss.x);
    atomicAdd(&cstats[(b * O + o + 1) * 2 + 0], s.y);
    atomicAdd(&cstats[(b * O + o + 1) * 2 + 1], ss.y);
    atomicAdd(&cstats[(b * O + o + 2) * 2 + 0], s.z);
    atomicAdd(&cstats[(b * O + o + 2) * 2 + 1], ss.z);
    atomicAdd(&cstats[(b * O + o + 3) * 2 + 0], s.w);
    atomicAdd(&cstats[(b * O + o + 3) * 2 + 1], ss.w);
  }
}

// in-place: featdst = lrelu((featdst - mean) * rsqrt(var + eps))
__global__ void finalize_kernel(const float* __restrict__ cstats,
                                float* __restrict__ featdst, int O) {
  int i = blockIdx.x * 256 + threadIdx.x;
  int o = i % O;
  int bn = i / O;
  int b = bn >> 11;
  float s = cstats[(b * O + o) * 2 + 0];
  float ss = cstats[(b * O + o) * 2 + 1];
  constexpr float inv = 1.f / ((float)N * KNN);
  float m = s * inv;
  float v = fmaxf(ss * inv - m * m, 0.f);
  float* p = &featdst[(size_t)bn * FD + o];
  float e = (*p - m) * rsqrtf(v + EPS);
  *p = lrelu(e);
}

// ---------------------------------------------------------------- 480 -> 128 stage
__global__ __launch_bounds__(256) void fstage_kernel(const float* __restrict__ feats,
                                                     const float* __restrict__ Wht,
                                                     float* __restrict__ fsum,
                                                     float* __restrict__ fss,
                                                     unsigned* __restrict__ fmaxu) {
  int blk = blockIdx.x;
  int b = blk >> 7;
  int n0 = (blk & 127) * 16;
  int tid = threadIdx.x;
  __shared__ float rows[16][FD];
  __shared__ float red[3][2][128];
  for (int i = tid; i < 16 * FD; i += 256) {
    int r = i / FD, c = i - r * FD;
    rows[r][c] = feats[(size_t)(b * N + n0 + r) * FD + c];
  }
  __syncthreads();
  int o = tid & 127, g = tid >> 7;
  float acc[8] = {};
  for (int c = 0; c < FD; ++c) {
    float w = Wht[c * 128 + o];
#pragma unroll
    for (int j = 0; j < 8; ++j) acc[j] += w * rows[g * 8 + j][c];
  }
  float s = 0.f, ss = 0.f, mx = -3.4e38f;
#pragma unroll
  for (int j = 0; j < 8; ++j) {
    float f = acc[j];
    s += f;
    ss += f * f;
    mx = fmaxf(mx, f);
  }
  red[0][g][o] = s;
  red[1][g][o] = ss;
  red[2][g][o] = mx;
  __syncthreads();
  if (g == 0) {
    s += red[0][1][o];
    ss += red[1][1][o];
    mx = fmaxf(mx, red[2][1][o]);
    atomicAdd(&fsum[b * 128 + o], s);
    atomicAdd(&fss[b * 128 + o], ss);
    unsigned u = __float_as_uint(mx);
    u = (u & 0x80000000u) ? ~u : (u | 0x80000000u);
    atomicMax(&fmaxu[b * 128 + o], u);
  }
}

// ---------------------------------------------------------------- head
__global__ __launch_bounds__(128) void head_kernel(const float* __restrict__ fsum,
                                                   const float* __restrict__ fss,
                                                   const unsigned* __restrict__ fmaxu,
                                                   const float* __restrict__ fc1w,
                                                   const float* __restrict__ fc1b,
                                                   const float* __restrict__ fc2w,
                                                   const float* __restrict__ fc2b,
                                                   void* __restrict__ out,
                                                   const int* __restrict__ flag) {
  int b = blockIdx.x, o = threadIdx.x;
  __shared__ float gs[128], t1[128], ys[128];
  constexpr float invN = 1.f / N;
  float m = fsum[b * 128 + o] * invN;
  float v = fmaxf(fss[b * 128 + o] * invN - m * m, 0.f);
  unsigned u = fmaxu[b * 128 + o];
  unsigned bits = (u & 0x80000000u) ? (u ^ 0x80000000u) : ~u;
  float fx = __uint_as_float(bits);
  gs[o] = lrelu((fx - m) * rsqrtf(v + EPS));
  __syncthreads();
  float a = fc1b[o];
  for (int c = 0; c < 128; ++c) a += fc1w[o * 128 + c] * gs[c];
  t1[o] = a;
  __syncthreads();
  float mm = 0.f;
  for (int c = 0; c < 128; ++c) mm += t1[c];
  mm *= (1.f / 128);
  float vv = 0.f;
  for (int c = 0; c < 128; ++c) {
    float d = t1[c] - mm;
    vv += d * d;
  }
  vv *= (1.f / 128);
  ys[o] = lrelu((a - mm) * rsqrtf(vv + EPS));
  __syncthreads();
  float r = fc2b[o];
  for (int c = 0; c < 128; ++c) r += fc2w[o * 128 + c] * ys[c];
  if (flag[0])
    ((float*)out)[b * 128 + o] = r;
  else
    ((bf16*)out)[b * 128 + o] = __float2bfloat16(r);
}

// ---------------------------------------------------------------- driver
template <int C, int O>
static void run_layer(const float* h, int hstride, float* featdst, const float* Wp,
                      float* cstats, float* dist, float* projb, int* idxb,
                      hipStream_t stream) {
  constexpr int NSEL = B * N / 4;
  constexpr int NPROJ = (2 * O / 64) * (B * N / 64);
  dist_kernel<C><<<dim3(N / 128, N / 128, B), 256, 0, stream>>>(h, hstride, dist);
  selproj_kernel<C, 2 * O><<<NSEL + NPROJ, 256, 0, stream>>>(dist, idxb, h, hstride, Wp,
                                                             projb);
  edge_reduce_kernel<O><<<B * N / 4, 256, 0, stream>>>(projb, idxb, cstats, featdst);
  finalize_kernel<<<B * N * O / 256, 256, 0, stream>>>(cstats, featdst, O);
}

extern "C" void kernel_launch(void* const* d_in, const int* in_sizes, int n_in,
                              void* d_out, int out_size, void* d_ws, size_t ws_size,
                              hipStream_t stream) {
  float* ws = (float*)d_ws;
  float* xf = ws + O_XF;
  float* feats = ws + O_FEATS;
  float* dist = ws + O_DIST;
  float* projb = ws + O_PROJ;
  int* idxb = (int*)(ws + O_IDX);
  int* flag = (int*)(ws + O_FLAG);

  prep_kernel<<<(PREP_TOTAL + 255) / 256, 256, 0, stream>>>(
      d_in[0], d_in[2], d_in[3], d_in[4], d_in[5], d_in[6], d_in[7], d_in[8], d_in[9],
      d_in[10], ws);

  run_layer<3, 32>(xf, 3, feats + 0, ws + O_WP0, ws + O_CS0, dist, projb, idxb, stream);
  run_layer<32, 64>(feats + 0, FD, feats + 32, ws + O_WP1, ws + O_CS1, dist, projb, idxb,
                    stream);
  run_layer<64, 128>(feats + 32, FD, feats + 96, ws + O_WP2, ws + O_CS2, dist, projb, idxb,
                     stream);
  run_layer<128, 256>(feats + 96, FD, feats + 224, ws + O_WP3, ws + O_CS3, dist, projb,
                      idxb, stream);

  fstage_kernel<<<B * 128, 256, 0, stream>>>(feats, ws + O_WHT, ws + O_FSUM, ws + O_FSS,
                                             (unsigned*)(ws + O_FMAX));
  head_kernel<<<B, 128, 0, stream>>>(ws + O_FSUM, ws + O_FSS, (unsigned*)(ws + O_FMAX),
                                     ws + O_F1W, ws + O_F1B, ws + O_F2W, ws + O_F2B, d_out,
                                     flag);
}